// Round 5
// baseline (174.579 us; speedup 1.0000x reference)
//
#include <hip/hip_runtime.h>
#include <hip/hip_bf16.h>
#include <stdint.h>

#define DIM   1024
#define NH    16
#define HDIM  64
#define SEQ   2048
#define BATCH 2
#define BHN   32            // BATCH*NH
#define MTOK  4096          // BATCH*SEQ
#define SC2   0.18033688f   // (1/sqrt(64)) * log2(e)

using u16 = unsigned short;
using u32 = unsigned int;
typedef __attribute__((ext_vector_type(8))) short short8;   // MFMA A/B frag (8 bf16)
typedef __attribute__((ext_vector_type(4))) float f32x4;    // 16x16 MFMA C/D frag
typedef __attribute__((ext_vector_type(16))) float f32x16;  // 32x32 MFMA C/D frag

__device__ __forceinline__ u16 f2bf(float f) {
  __hip_bfloat16 h = __float2bfloat16(f);
  return *reinterpret_cast<u16*>(&h);
}
__device__ __forceinline__ float bf2f(u16 u) {
  u32 v = ((u32)u) << 16;
  return __builtin_bit_cast(float, v);
}
__device__ __forceinline__ u32 pk2(float lo, float hi) {
  return (u32)f2bf(lo) | ((u32)f2bf(hi) << 16);
}
// hardware packed f32->bf16 (RNE), 1 instr for 2 values
__device__ __forceinline__ u32 cvtpk(float lo, float hi) {
  u32 r;
  asm("v_cvt_pk_bf16_f32 %0, %1, %2" : "=v"(r) : "v"(lo), "v"(hi));
  return r;
}

// async global->LDS, 16B per lane. lds base must be wave-uniform; gsrc per-lane.
__device__ __forceinline__ void gload16(const void* g, void* lds) {
  __builtin_amdgcn_global_load_lds(
      (const __attribute__((address_space(1))) u32*)g,
      (__attribute__((address_space(3))) u32*)lds, 16, 0, 0);
}

// ---------------- fused prep: fp32->bf16 x3 + RoPE cos/sin table ----------------
#define PREP_A 1048576              // x: MTOK*DIM/4
#define PREP_B 1835008              // + qkv_w: 3*DIM*DIM/4
#define PREP_C 2097152              // + proj_w: DIM*DIM/4
#define PREP_E 2162688              // + tab: SEQ*32
__global__ void k_prep(const float4* __restrict__ x, const float4* __restrict__ qw,
                       const float4* __restrict__ pw, ushort4* __restrict__ xb,
                       ushort4* __restrict__ qwb, ushort4* __restrict__ pwb,
                       float2* __restrict__ tab) {
  int i = blockIdx.x * blockDim.x + threadIdx.x;
  if (i < PREP_A) {
    float4 v = x[i];
    xb[i] = make_ushort4(f2bf(v.x), f2bf(v.y), f2bf(v.z), f2bf(v.w));
  } else if (i < PREP_B) {
    int j = i - PREP_A;
    float4 v = qw[j];
    qwb[j] = make_ushort4(f2bf(v.x), f2bf(v.y), f2bf(v.z), f2bf(v.w));
  } else if (i < PREP_C) {
    int j = i - PREP_B;
    float4 v = pw[j];
    pwb[j] = make_ushort4(f2bf(v.x), f2bf(v.y), f2bf(v.z), f2bf(v.w));
  } else if (i < PREP_E) {
    int j = i - PREP_C;
    int n = j >> 5, f = j & 31;
    float inv = powf(10000.f, -(2.f * f) / 64.f);
    float s, c;
    sincosf((float)n * inv, &s, &c);
    tab[j] = make_float2(c, s);
  }
}

// ---------------- bf16 GEMM: C = A * Bt^T, 128x128 tile, BK=64 ----------------
// EPI=0: fp32 out + bias (proj). EPI=1: bias + fused RoPE + bf16 scatter to q/k/vt.
template <int EPI>
__global__ __launch_bounds__(256, 2) void k_gemm(
    const u16* __restrict__ A, const u16* __restrict__ Bt,
    const float* __restrict__ bias, int K,
    float* __restrict__ out_f, u16* __restrict__ qb, u16* __restrict__ kb,
    u16* __restrict__ vtb, const float2* __restrict__ tab) {
  __shared__ u16 As[128 * 64];
  __shared__ u16 Bs[128 * 64];
  const int tid = threadIdx.x;
  const int wid = tid >> 6, lane = tid & 63;
  const int lq = lane & 15, g = lane >> 4;
  const int wr = wid >> 1, wc = wid & 1;
  const int brow = blockIdx.y * 128;
  const int bcol = blockIdx.x * 128;
  f32x4 acc[4][4] = {};
  const u16* Ab = A + (size_t)brow * K;
  const u16* Bb = Bt + (size_t)bcol * K;

  for (int k0 = 0; k0 < K; k0 += 64) {
#pragma unroll
    for (int t = 0; t < 4; t++) {
      int rl = wid * 32 + t * 8 + (lane >> 3);
      int cs = (lane & 7) ^ (rl & 7);
      gload16(Ab + (size_t)rl * K + k0 + cs * 8, &As[(wid * 32 + t * 8) * 64]);
      gload16(Bb + (size_t)rl * K + k0 + cs * 8, &Bs[(wid * 32 + t * 8) * 64]);
    }
    __syncthreads();
#pragma unroll
    for (int kc = 0; kc < 2; kc++) {
      short8 af[4], bfr[4];
#pragma unroll
      for (int mt = 0; mt < 4; mt++) {
        int r = wr * 64 + mt * 16 + lq;
        af[mt] = *reinterpret_cast<const short8*>(&As[r * 64 + (((kc * 4 + g) ^ (r & 7)) * 8)]);
      }
#pragma unroll
      for (int nt = 0; nt < 4; nt++) {
        int r = wc * 64 + nt * 16 + lq;
        bfr[nt] = *reinterpret_cast<const short8*>(&Bs[r * 64 + (((kc * 4 + g) ^ (r & 7)) * 8)]);
      }
#pragma unroll
      for (int mt = 0; mt < 4; mt++)
#pragma unroll
        for (int nt = 0; nt < 4; nt++)
          acc[mt][nt] = __builtin_amdgcn_mfma_f32_16x16x32_bf16(af[mt], bfr[nt], acc[mt][nt], 0, 0, 0);
    }
    __syncthreads();
  }

#pragma unroll
  for (int mt = 0; mt < 4; mt++) {
    int row0 = brow + wr * 64 + mt * 16 + g * 4;
#pragma unroll
    for (int nt = 0; nt < 4; nt++) {
      int col = bcol + wc * 64 + nt * 16 + lq;
      float bv = bias[col];
#pragma unroll
      for (int r = 0; r < 4; r++) {
        float v = acc[mt][nt][r] + bv;
        int rr = row0 + r;
        if (EPI == 0) {
          out_f[(size_t)rr * DIM + col] = v;
        } else {
          // which is uniform per block (bcol multiples of 128 align to 1024)
          int which = col >> 10, hd = col & 1023, hdh = hd >> 6, d = hd & 63;
          int bb = rr >> 11, n = rr & 2047;
          if (which == 2) {
            vtb[(((size_t)bb * NH + hdh) * HDIM + d) * SEQ + n] = f2bf(v);  // V transposed
          } else {
            // fused RoPE: partner value (col^1) lives in adjacent lane
            float p = __shfl_xor(v, 1);
            float2 cs = tab[n * 32 + (d >> 1)];
            float vv = (d & 1) ? fmaf(p, cs.y, v * cs.x)   // o' = e*s + o*c
                               : fmaf(-p, cs.y, v * cs.x); // e' = e*c - o*s
            u16 xo = f2bf(vv);
            if (which == 0) qb[(((size_t)bb * NH + hdh) * SEQ + n) * HDIM + d] = xo;
            else            kb[(((size_t)bb * NH + hdh) * SEQ + n) * HDIM + d] = xo;
          }
        }
      }
    }
  }
}

// ---------------- flash attention: 8 waves, in-block KV-split x2 + r4 pipeline ----------------
// grid 512 (XCD-swizzled), 512 thr. Wave w: q-rows (w&3)*32 of the 128-row q-tile,
// kv-half (w>>2). Per half: own K/V double-buffer, 16 tiles of 64.
// Counted s_waitcnt vmcnt(4), raw barriers (no mid-loop vmcnt(0) drain).
// S^T = K*Q^T (32x32x16), per-lane online softmax, cvt_pk+permlane32_swap P-pack,
// O^T = V^T*P^T. Halves merged in-block via LDS alias. Defer-max rescale.
__global__ __launch_bounds__(512, 4) void k_attn(
    const u16* __restrict__ qb, const u16* __restrict__ kb,
    const u16* __restrict__ vtb, u16* __restrict__ aout) {
  __shared__ __align__(16) char smem[65536];   // [half][buf][K 8KB | V 8KB]
  float* Om = (float*)smem;                    // merge alias: [128][65] f32
  float* Ml = (float*)(smem + 128 * 65 * 4);   // merge alias: [128][2]

  const int tid = threadIdx.x;
  const int wid = tid >> 6, lane = tid & 63;
  const int wq = wid & 3, sh = wid >> 2;
  const int l31 = lane & 31, h = lane >> 5;

  // XCD-aware decode: bid&7 = XCD; 4 consecutive heads per XCD (2MB KV / XCD-L2)
  const int bid = blockIdx.x;
  const int xcd = bid & 7, slot = bid >> 3;
  const int bh = xcd * 4 + (slot >> 4);
  const int qt = slot & 15;
  const int b = bh >> 4, hh = bh & 15;
  const int q0 = qt * 128 + wq * 32;

  const u16* kbase = kb + (size_t)bh * SEQ * HDIM;
  const u16* vbase = vtb + (size_t)bh * HDIM * SEQ;

  // Q B-frags: chunk c -> d = c*16 + h*8 + j
  const u16* qrow = qb + ((size_t)bh * SEQ + q0 + l31) * HDIM;
  short8 qf[4];
#pragma unroll
  for (int c = 0; c < 4; c++)
    qf[c] = *reinterpret_cast<const short8*>(qrow + c * 16 + h * 8);

  // hoisted swizzled LDS byte-offsets (row l31; +4096 for rows 32-63)
  int koff[4];
#pragma unroll
  for (int c = 0; c < 4; c++)
    koff[c] = l31 * 128 + (((2 * c + h) ^ (l31 & 7)) << 4);

  f32x16 oA = {}, oB = {};
  float m = -INFINITY, lsum = 0.f;

  char* base = smem + sh * 32768;          // this half's region

  auto stage = [&](int buf, int kv0) {     // 4 gloads/lane (2 K + 2 V)
    char* kd = base + buf * 16384;
#pragma unroll
    for (int t = 0; t < 2; t++) {
      int rl = wq * 16 + t * 8 + (lane >> 3);
      int cs = (lane & 7) ^ (rl & 7);      // pre-swizzled global source
      gload16(kbase + (size_t)(kv0 + rl) * HDIM + cs * 8, kd + (wq * 16 + t * 8) * 128);
      gload16(vbase + (size_t)rl * SEQ + kv0 + cs * 8, kd + 8192 + (wq * 16 + t * 8) * 128);
    }
  };

  const int kvb = sh * (SEQ / 2);
  stage(0, kvb);
  stage(1, kvb + 64);

  const int NT = SEQ / 128;                // 16 tiles per half
  for (int t = 0; t < NT; ++t) {
    const int cur = t & 1;
    if (t < NT - 1) asm volatile("s_waitcnt vmcnt(4)" ::: "memory");
    else            asm volatile("s_waitcnt vmcnt(0)" ::: "memory");
    __builtin_amdgcn_s_barrier();

    const char* kbp = base + cur * 16384;
    const char* vbp = kbp + 8192;

    // S^T = K * Q^T : s0 = kv 0..31 of tile, s1 = kv 32..63; lane col q = l31
    f32x16 s0 = {}, s1 = {};
    __builtin_amdgcn_s_setprio(1);
#pragma unroll
    for (int c = 0; c < 4; c++) {
      short8 k0 = *reinterpret_cast<const short8*>(kbp + koff[c]);
      short8 k1 = *reinterpret_cast<const short8*>(kbp + koff[c] + 4096);
      s0 = __builtin_amdgcn_mfma_f32_32x32x16_bf16(k0, qf[c], s0, 0, 0, 0);
      s1 = __builtin_amdgcn_mfma_f32_32x32x16_bf16(k1, qf[c], s1, 0, 0, 0);
    }
    __builtin_amdgcn_s_setprio(0);

    // V A-frags issued early: LDS latency hides under softmax VALU
    short8 vf0[4], vf1[4];
#pragma unroll
    for (int c = 0; c < 4; c++) {
      vf0[c] = *reinterpret_cast<const short8*>(vbp + koff[c]);
      vf1[c] = *reinterpret_cast<const short8*>(vbp + koff[c] + 4096);
    }

    // online softmax; lane owns q = l31 (paired across lane^32)
    float tm[8];
#pragma unroll
    for (int r = 0; r < 8; r++)
      tm[r] = fmaxf(fmaxf(s0[r], s1[r]), fmaxf(s0[r + 8], s1[r + 8]));
    float ta = fmaxf(fmaxf(tm[0], tm[1]), tm[2]);
    float tb = fmaxf(fmaxf(tm[3], tm[4]), tm[5]);
    float tc = fmaxf(tm[6], tm[7]);
    float tmax = fmaxf(fmaxf(ta, tb), tc);
    tmax = fmaxf(tmax, __shfl_xor(tmax, 32));

    float alpha = 1.f;
    if (__any(tmax - m > 61.0f)) {     // defer-max: p bounded by 2^11
      float mnew = fmaxf(m, tmax);
      alpha = exp2f((m - mnew) * SC2);
      m = mnew;
#pragma unroll
      for (int r = 0; r < 16; r++) { oA[r] *= alpha; oB[r] *= alpha; }
    }
    const float nms = -m * SC2;
#pragma unroll
    for (int r = 0; r < 16; r++) s0[r] = exp2f(fmaf(s0[r], SC2, nms));
#pragma unroll
    for (int r = 0; r < 16; r++) s1[r] = exp2f(fmaf(s1[r], SC2, nms));
    float pa = 0.f, pb = 0.f, pc = 0.f, pd = 0.f;
#pragma unroll
    for (int r = 0; r < 4; r++) {
      pa += s0[r] + s0[r + 4];
      pb += s0[r + 8] + s0[r + 12];
      pc += s1[r] + s1[r + 4];
      pd += s1[r + 8] + s1[r + 12];
    }
    float psum = (pa + pb) + (pc + pd);
    psum += __shfl_xor(psum, 32);
    lsum = lsum * alpha + psum;

    // pack P to bf16 B-frags: 4 cvt_pk + 2 permlane32_swap per chunk (T12)
    short8 pf[4];
    {
      union { u32 u[4]; short8 v; } pp;
      u32 a0, a1, b0, b1;
      a0 = cvtpk(s0[0], s0[1]);  a1 = cvtpk(s0[2], s0[3]);
      b0 = cvtpk(s0[4], s0[5]);  b1 = cvtpk(s0[6], s0[7]);
      { auto r0 = __builtin_amdgcn_permlane32_swap(a0, b0, false, false);
        auto r1 = __builtin_amdgcn_permlane32_swap(a1, b1, false, false);
        pp.u[0] = r0[0]; pp.u[1] = r1[0]; pp.u[2] = r0[1]; pp.u[3] = r1[1]; pf[0] = pp.v; }
      a0 = cvtpk(s0[8], s0[9]);   a1 = cvtpk(s0[10], s0[11]);
      b0 = cvtpk(s0[12], s0[13]); b1 = cvtpk(s0[14], s0[15]);
      { auto r0 = __builtin_amdgcn_permlane32_swap(a0, b0, false, false);
        auto r1 = __builtin_amdgcn_permlane32_swap(a1, b1, false, false);
        pp.u[0] = r0[0]; pp.u[1] = r1[0]; pp.u[2] = r0[1]; pp.u[3] = r1[1]; pf[1] = pp.v; }
      a0 = cvtpk(s1[0], s1[1]);  a1 = cvtpk(s1[2], s1[3]);
      b0 = cvtpk(s1[4], s1[5]);  b1 = cvtpk(s1[6], s1[7]);
      { auto r0 = __builtin_amdgcn_permlane32_swap(a0, b0, false, false);
        auto r1 = __builtin_amdgcn_permlane32_swap(a1, b1, false, false);
        pp.u[0] = r0[0]; pp.u[1] = r1[0]; pp.u[2] = r0[1]; pp.u[3] = r1[1]; pf[2] = pp.v; }
      a0 = cvtpk(s1[8], s1[9]);   a1 = cvtpk(s1[10], s1[11]);
      b0 = cvtpk(s1[12], s1[13]); b1 = cvtpk(s1[14], s1[15]);
      { auto r0 = __builtin_amdgcn_permlane32_swap(a0, b0, false, false);
        auto r1 = __builtin_amdgcn_permlane32_swap(a1, b1, false, false);
        pp.u[0] = r0[0]; pp.u[1] = r1[0]; pp.u[2] = r0[1]; pp.u[3] = r1[1]; pf[3] = pp.v; }
    }

    // O^T += V^T * P^T : oA = d 0..31, oB = d 32..63; lane col q = l31
    __builtin_amdgcn_s_setprio(1);
#pragma unroll
    for (int c = 0; c < 4; c++) {
      oA = __builtin_amdgcn_mfma_f32_32x32x16_bf16(vf0[c], pf[c], oA, 0, 0, 0);
      oB = __builtin_amdgcn_mfma_f32_32x32x16_bf16(vf1[c], pf[c], oB, 0, 0, 0);
    }
    __builtin_amdgcn_s_setprio(0);

    // all my LDS reads complete -> safe for others to overwrite after barrier
    asm volatile("s_waitcnt lgkmcnt(0)" ::: "memory");
    __builtin_amdgcn_s_barrier();
    if (t + 2 < NT) stage(cur, kvb + (t + 2) * 64);   // refill the freed buffer
  }

  // ---- in-block merge of the two kv-halves (LDS aliases K/V region) ----
  const int ql = wq * 32 + l31;
  if (sh == 1) {
    if (h == 0) { Ml[ql * 2] = m; Ml[ql * 2 + 1] = lsum; }
#pragma unroll
    for (int g = 0; g < 4; g++)
#pragma unroll
      for (int i = 0; i < 4; i++) {
        Om[ql * 65 + 8 * g + 4 * h + i]      = oA[4 * g + i];
        Om[ql * 65 + 32 + 8 * g + 4 * h + i] = oB[4 * g + i];
      }
  }
  __syncthreads();
  if (sh == 0) {
    float m1 = Ml[ql * 2], l1 = Ml[ql * 2 + 1];
    float M = fmaxf(m, m1);
    float a0 = exp2f((m - M) * SC2);
    float a1 = exp2f((m1 - M) * SC2);
    float invl = 1.0f / (lsum * a0 + l1 * a1);

    int n = q0 + l31;
    u16* op = aout + ((size_t)(b * SEQ + n)) * DIM + hh * HDIM;
#pragma unroll
    for (int g = 0; g < 4; g++) {
      float vA[4], vB[4];
#pragma unroll
      for (int i = 0; i < 4; i++) {
        vA[i] = (oA[4 * g + i] * a0 + Om[ql * 65 + 8 * g + 4 * h + i] * a1) * invl;
        vB[i] = (oB[4 * g + i] * a0 + Om[ql * 65 + 32 + 8 * g + 4 * h + i] * a1) * invl;
      }
      *reinterpret_cast<uint2*>(op + 8 * g + 4 * h) = make_uint2(pk2(vA[0], vA[1]), pk2(vA[2], vA[3]));
      *reinterpret_cast<uint2*>(op + 32 + 8 * g + 4 * h) = make_uint2(pk2(vB[0], vB[1]), pk2(vB[2], vB[3]));
    }
  }
}

// ---------------- launch ----------------
extern "C" void kernel_launch(void* const* d_in, const int* in_sizes, int n_in,
                              void* d_out, int out_size, void* d_ws, size_t ws_size,
                              hipStream_t stream) {
  (void)in_sizes; (void)n_in; (void)out_size; (void)ws_size;
  const float* x      = (const float*)d_in[0];
  const float* qkv_w  = (const float*)d_in[1];
  const float* qkv_b  = (const float*)d_in[2];
  const float* proj_w = (const float*)d_in[3];
  const float* proj_b = (const float*)d_in[4];
  float* out = (float*)d_out;

  char* w = (char*)d_ws;
  u16* xb     = (u16*)w;  w += (size_t)MTOK * DIM * 2;
  u16* wqkvb  = (u16*)w;  w += (size_t)3 * DIM * DIM * 2;
  u16* wprojb = (u16*)w;  w += (size_t)DIM * DIM * 2;
  u16* qb     = (u16*)w;  w += (size_t)BHN * SEQ * HDIM * 2;
  u16* kb     = (u16*)w;  w += (size_t)BHN * SEQ * HDIM * 2;
  u16* vtb    = (u16*)w;  w += (size_t)BHN * SEQ * HDIM * 2;
  u16* aout   = (u16*)w;  w += (size_t)MTOK * DIM * 2;
  float2* tab = (float2*)w;

  k_prep<<<(PREP_E + 255) / 256, 256, 0, stream>>>(
      (const float4*)x, (const float4*)qkv_w, (const float4*)proj_w,
      (ushort4*)xb, (ushort4*)wqkvb, (ushort4*)wprojb, tab);

  k_gemm<1><<<dim3(3 * DIM / 128, MTOK / 128), 256, 0, stream>>>(
      xb, wqkvb, qkv_b, DIM, nullptr, qb, kb, vtb, tab);

  k_attn<<<512, 512, 0, stream>>>(qb, kb, vtb, aout);

  k_gemm<0><<<dim3(DIM / 128, MTOK / 128), 256, 0, stream>>>(
      aout, wprojb, proj_b, DIM, out, nullptr, nullptr, nullptr, nullptr);
}

// Round 6
// 156.594 us; speedup vs baseline: 1.1149x; 1.1149x over previous
//
#include <hip/hip_runtime.h>
#include <hip/hip_bf16.h>
#include <stdint.h>

#define DIM   1024
#define NH    16
#define HDIM  64
#define SEQ   2048
#define BATCH 2
#define BHN   32            // BATCH*NH
#define MTOK  4096          // BATCH*SEQ
#define SC2   0.18033688f   // (1/sqrt(64)) * log2(e)

using u16 = unsigned short;
using u32 = unsigned int;
typedef __attribute__((ext_vector_type(8))) short short8;   // MFMA A/B frag (8 bf16)
typedef __attribute__((ext_vector_type(4))) float f32x4;    // 16x16 MFMA C/D frag
typedef __attribute__((ext_vector_type(16))) float f32x16;  // 32x32 MFMA C/D frag

__device__ __forceinline__ u16 f2bf(float f) {
  __hip_bfloat16 h = __float2bfloat16(f);
  return *reinterpret_cast<u16*>(&h);
}
__device__ __forceinline__ float bf2f(u16 u) {
  u32 v = ((u32)u) << 16;
  return __builtin_bit_cast(float, v);
}
__device__ __forceinline__ u32 pk2(float lo, float hi) {
  return (u32)f2bf(lo) | ((u32)f2bf(hi) << 16);
}
// hardware packed f32->bf16 (RNE), 1 instr for 2 values
__device__ __forceinline__ u32 cvtpk(float lo, float hi) {
  u32 r;
  asm("v_cvt_pk_bf16_f32 %0, %1, %2" : "=v"(r) : "v"(lo), "v"(hi));
  return r;
}

// async global->LDS, 16B per lane. lds base must be wave-uniform; gsrc per-lane.
__device__ __forceinline__ void gload16(const void* g, void* lds) {
  __builtin_amdgcn_global_load_lds(
      (const __attribute__((address_space(1))) u32*)g,
      (__attribute__((address_space(3))) u32*)lds, 16, 0, 0);
}

// ---------------- fused prep: fp32->bf16 x3 + RoPE cos/sin table ----------------
#define PREP_A 1048576              // x: MTOK*DIM/4
#define PREP_B 1835008              // + qkv_w: 3*DIM*DIM/4
#define PREP_C 2097152              // + proj_w: DIM*DIM/4
#define PREP_E 2162688              // + tab: SEQ*32
__global__ void k_prep(const float4* __restrict__ x, const float4* __restrict__ qw,
                       const float4* __restrict__ pw, ushort4* __restrict__ xb,
                       ushort4* __restrict__ qwb, ushort4* __restrict__ pwb,
                       float2* __restrict__ tab) {
  int i = blockIdx.x * blockDim.x + threadIdx.x;
  if (i < PREP_A) {
    float4 v = x[i];
    xb[i] = make_ushort4(f2bf(v.x), f2bf(v.y), f2bf(v.z), f2bf(v.w));
  } else if (i < PREP_B) {
    int j = i - PREP_A;
    float4 v = qw[j];
    qwb[j] = make_ushort4(f2bf(v.x), f2bf(v.y), f2bf(v.z), f2bf(v.w));
  } else if (i < PREP_C) {
    int j = i - PREP_B;
    float4 v = pw[j];
    pwb[j] = make_ushort4(f2bf(v.x), f2bf(v.y), f2bf(v.z), f2bf(v.w));
  } else if (i < PREP_E) {
    int j = i - PREP_C;
    int n = j >> 5, f = j & 31;
    float inv = powf(10000.f, -(2.f * f) / 64.f);
    float s, c;
    sincosf((float)n * inv, &s, &c);
    tab[j] = make_float2(c, s);
  }
}

// ---------------- bf16 GEMM: C = A * Bt^T, 128x128 tile, BK=64 ----------------
// EPI=0: fp32 out + bias (proj). EPI=1: bias + fused RoPE + bf16 scatter to q/k/vt.
template <int EPI>
__global__ __launch_bounds__(256, 2) void k_gemm(
    const u16* __restrict__ A, const u16* __restrict__ Bt,
    const float* __restrict__ bias, int K,
    float* __restrict__ out_f, u16* __restrict__ qb, u16* __restrict__ kb,
    u16* __restrict__ vtb, const float2* __restrict__ tab) {
  __shared__ u16 As[128 * 64];
  __shared__ u16 Bs[128 * 64];
  const int tid = threadIdx.x;
  const int wid = tid >> 6, lane = tid & 63;
  const int lq = lane & 15, g = lane >> 4;
  const int wr = wid >> 1, wc = wid & 1;
  const int brow = blockIdx.y * 128;
  const int bcol = blockIdx.x * 128;
  f32x4 acc[4][4] = {};
  const u16* Ab = A + (size_t)brow * K;
  const u16* Bb = Bt + (size_t)bcol * K;

  for (int k0 = 0; k0 < K; k0 += 64) {
#pragma unroll
    for (int t = 0; t < 4; t++) {
      int rl = wid * 32 + t * 8 + (lane >> 3);
      int cs = (lane & 7) ^ (rl & 7);
      gload16(Ab + (size_t)rl * K + k0 + cs * 8, &As[(wid * 32 + t * 8) * 64]);
      gload16(Bb + (size_t)rl * K + k0 + cs * 8, &Bs[(wid * 32 + t * 8) * 64]);
    }
    __syncthreads();
#pragma unroll
    for (int kc = 0; kc < 2; kc++) {
      short8 af[4], bfr[4];
#pragma unroll
      for (int mt = 0; mt < 4; mt++) {
        int r = wr * 64 + mt * 16 + lq;
        af[mt] = *reinterpret_cast<const short8*>(&As[r * 64 + (((kc * 4 + g) ^ (r & 7)) * 8)]);
      }
#pragma unroll
      for (int nt = 0; nt < 4; nt++) {
        int r = wc * 64 + nt * 16 + lq;
        bfr[nt] = *reinterpret_cast<const short8*>(&Bs[r * 64 + (((kc * 4 + g) ^ (r & 7)) * 8)]);
      }
#pragma unroll
      for (int mt = 0; mt < 4; mt++)
#pragma unroll
        for (int nt = 0; nt < 4; nt++)
          acc[mt][nt] = __builtin_amdgcn_mfma_f32_16x16x32_bf16(af[mt], bfr[nt], acc[mt][nt], 0, 0, 0);
    }
    __syncthreads();
  }

#pragma unroll
  for (int mt = 0; mt < 4; mt++) {
    int row0 = brow + wr * 64 + mt * 16 + g * 4;
#pragma unroll
    for (int nt = 0; nt < 4; nt++) {
      int col = bcol + wc * 64 + nt * 16 + lq;
      float bv = bias[col];
#pragma unroll
      for (int r = 0; r < 4; r++) {
        float v = acc[mt][nt][r] + bv;
        int rr = row0 + r;
        if (EPI == 0) {
          out_f[(size_t)rr * DIM + col] = v;
        } else {
          int which = col >> 10, hd = col & 1023, hdh = hd >> 6, d = hd & 63;
          int bb = rr >> 11, n = rr & 2047;
          if (which == 2) {
            vtb[(((size_t)bb * NH + hdh) * HDIM + d) * SEQ + n] = f2bf(v);  // V transposed
          } else {
            // fused RoPE: partner value (col^1) lives in adjacent lane
            float p = __shfl_xor(v, 1);
            float2 cs = tab[n * 32 + (d >> 1)];
            float vv = (d & 1) ? fmaf(p, cs.y, v * cs.x)   // o' = e*s + o*c
                               : fmaf(-p, cs.y, v * cs.x); // e' = e*c - o*s
            u16 xo = f2bf(vv);
            if (which == 0) qb[(((size_t)bb * NH + hdh) * SEQ + n) * HDIM + d] = xo;
            else            kb[(((size_t)bb * NH + hdh) * SEQ + n) * HDIM + d] = xo;
          }
        }
      }
    }
  }
}

// ---------------- flash attention: barrier-free wave-private pipeline ----------------
// grid 1024 (XCD-swizzled), 128 thr = 2 waves. Block owns 64 q-rows; wave w owns
// KV-half w (1024 kv) in private 16KB LDS (dbuf x [K 4KB | V 4KB]), tiles of 32 kv.
// Each wave: 2 independent 32-q-row chains (QK 32x32x16 swapped, per-lane softmax,
// cvt_pk+permlane pack, PV). No mid-loop barriers: counted vmcnt(8) against own
// loads only. Halves merged at the end via LDS alias (2 barriers total).
__global__ __launch_bounds__(128, 2) void k_attn(
    const u16* __restrict__ qg, const u16* __restrict__ kg,
    const u16* __restrict__ vg, u16* __restrict__ aout) {
  __shared__ __align__(16) char smem[32768];   // [wave][buf][K 4KB | V 4KB]
  const int tid = threadIdx.x;
  const int wid = tid >> 6, lane = tid & 63;
  const int l31 = lane & 31, h = lane >> 5;

  // XCD-aware decode: bid&7 = XCD; 4 consecutive heads per XCD (2MB KV / XCD-L2)
  const int bid = blockIdx.x;
  const int xcd = bid & 7, slot = bid >> 3;      // slot 0..127
  const int bh = xcd * 4 + (slot >> 5);
  const int qt = slot & 31;
  const int b = bh >> 4, hh = bh & 15;
  const int q0 = qt * 64;                         // block's 64 q-rows

  const u16* kbase = kg + (size_t)bh * SEQ * HDIM;
  const u16* vbase = vg + (size_t)bh * HDIM * SEQ;

  // Q B-frags for both q-chains: chunk c -> d = c*16 + h*8 + j
  short8 qf0[4], qf1[4];
  {
    const u16* qr0 = qg + ((size_t)bh * SEQ + q0 + l31) * HDIM;
    const u16* qr1 = qr0 + 32 * HDIM;
#pragma unroll
    for (int c = 0; c < 4; c++) {
      qf0[c] = *reinterpret_cast<const short8*>(qr0 + c * 16 + h * 8);
      qf1[c] = *reinterpret_cast<const short8*>(qr1 + c * 16 + h * 8);
    }
  }

  // hoisted swizzled LDS byte-offsets
  int koff[4], voff[2];
#pragma unroll
  for (int c = 0; c < 4; c++)
    koff[c] = l31 * 128 + (((2 * c + h) ^ (l31 & 7)) << 4);
#pragma unroll
  for (int c = 0; c < 2; c++)
    voff[c] = l31 * 64 + (((2 * c + h) ^ (l31 & 3)) << 4);

  f32x16 oA0 = {}, oB0 = {}, oA1 = {}, oB1 = {};
  float m0 = -INFINITY, ls0 = 0.f, m1 = -INFINITY, ls1 = 0.f;

  char* wbase = smem + wid * 16384;   // this wave's private region

  // stage one 32-kv tile: K 32x64 (128B rows), V 64x32 (64B rows), 8 gloads
  auto stage = [&](int buf, int kv0) {
    char* kd = wbase + buf * 8192;
#pragma unroll
    for (int i = 0; i < 4; i++) {
      int krow = 8 * i + (lane >> 3);
      int csk = (lane & 7) ^ (krow & 7);
      gload16(kbase + (size_t)(kv0 + krow) * HDIM + csk * 8, kd + i * 1024);
      int drow = 16 * i + (lane >> 2);
      int csv = (lane & 3) ^ (drow & 3);
      gload16(vbase + (size_t)drow * SEQ + kv0 + csv * 8, kd + 4096 + i * 1024);
    }
  };

  const int kvb = wid * (SEQ / 2);
  stage(0, kvb);
  stage(1, kvb + 32);

  const int NT = SEQ / 64;            // 32 tiles of 32 kv per wave
  for (int t = 0; t < NT; ++t) {
    const int cur = t & 1;
    if (t < NT - 1) asm volatile("s_waitcnt vmcnt(8)" ::: "memory");
    else            asm volatile("s_waitcnt vmcnt(0)" ::: "memory");
    const char* kbp = wbase + cur * 8192;
    const char* vbp = kbp + 4096;

    // S^T = K * Q^T for both q-chains (independent)
    short8 kf[4];
#pragma unroll
    for (int c = 0; c < 4; c++)
      kf[c] = *reinterpret_cast<const short8*>(kbp + koff[c]);
    f32x16 s0 = {}, s1 = {};
    __builtin_amdgcn_s_setprio(1);
#pragma unroll
    for (int c = 0; c < 4; c++) {
      s0 = __builtin_amdgcn_mfma_f32_32x32x16_bf16(kf[c], qf0[c], s0, 0, 0, 0);
      s1 = __builtin_amdgcn_mfma_f32_32x32x16_bf16(kf[c], qf1[c], s1, 0, 0, 0);
    }
    __builtin_amdgcn_s_setprio(0);

    // V A-frags (shared by both chains), issued early
    short8 vA[2], vB[2];
#pragma unroll
    for (int c = 0; c < 2; c++) {
      vA[c] = *reinterpret_cast<const short8*>(vbp + voff[c]);
      vB[c] = *reinterpret_cast<const short8*>(vbp + voff[c] + 2048);
    }

    // ---- softmax chain 0 (q-rows q0..q0+31), lane owns q=l31, kv split by reg/h ----
    float pA0, pB0;
    {
      float tm[4];
#pragma unroll
      for (int r = 0; r < 4; r++)
        tm[r] = fmaxf(fmaxf(s0[r], s0[r + 4]), fmaxf(s0[r + 8], s0[r + 12]));
      float tmax = fmaxf(fmaxf(tm[0], tm[1]), fmaxf(tm[2], tm[3]));
      tmax = fmaxf(tmax, __shfl_xor(tmax, 32));
      float alpha = 1.f;
      if (__any(tmax - m0 > 61.0f)) {
        float mnew = fmaxf(m0, tmax);
        alpha = exp2f((m0 - mnew) * SC2);
        m0 = mnew;
#pragma unroll
        for (int r = 0; r < 16; r++) { oA0[r] *= alpha; oB0[r] *= alpha; }
      }
      const float nms = -m0 * SC2;
#pragma unroll
      for (int r = 0; r < 16; r++) s0[r] = exp2f(fmaf(s0[r], SC2, nms));
      float pa = 0.f, pb = 0.f;
#pragma unroll
      for (int r = 0; r < 4; r++) {
        pa += s0[r] + s0[r + 4];
        pb += s0[r + 8] + s0[r + 12];
      }
      float psum = pa + pb;
      psum += __shfl_xor(psum, 32);
      ls0 = ls0 * alpha + psum;
      pA0 = alpha; pB0 = psum;  (void)pA0; (void)pB0;
    }
    // ---- softmax chain 1 ----
    {
      float tm[4];
#pragma unroll
      for (int r = 0; r < 4; r++)
        tm[r] = fmaxf(fmaxf(s1[r], s1[r + 4]), fmaxf(s1[r + 8], s1[r + 12]));
      float tmax = fmaxf(fmaxf(tm[0], tm[1]), fmaxf(tm[2], tm[3]));
      tmax = fmaxf(tmax, __shfl_xor(tmax, 32));
      float alpha = 1.f;
      if (__any(tmax - m1 > 61.0f)) {
        float mnew = fmaxf(m1, tmax);
        alpha = exp2f((m1 - mnew) * SC2);
        m1 = mnew;
#pragma unroll
        for (int r = 0; r < 16; r++) { oA1[r] *= alpha; oB1[r] *= alpha; }
      }
      const float nms = -m1 * SC2;
#pragma unroll
      for (int r = 0; r < 16; r++) s1[r] = exp2f(fmaf(s1[r], SC2, nms));
      float pa = 0.f, pb = 0.f;
#pragma unroll
      for (int r = 0; r < 4; r++) {
        pa += s1[r] + s1[r + 4];
        pb += s1[r + 8] + s1[r + 12];
      }
      float psum = pa + pb;
      psum += __shfl_xor(psum, 32);
      ls1 = ls1 * alpha + psum;
    }

    // pack P: per chain 8 cvt_pk + 4 permlane32_swap (T12)
    short8 pf0[2], pf1[2];
    {
      union { u32 u[4]; short8 v; } pp;
      u32 a0, a1, b0, b1;
      a0 = cvtpk(s0[0], s0[1]);  a1 = cvtpk(s0[2], s0[3]);
      b0 = cvtpk(s0[4], s0[5]);  b1 = cvtpk(s0[6], s0[7]);
      { auto r0 = __builtin_amdgcn_permlane32_swap(a0, b0, false, false);
        auto r1 = __builtin_amdgcn_permlane32_swap(a1, b1, false, false);
        pp.u[0] = r0[0]; pp.u[1] = r1[0]; pp.u[2] = r0[1]; pp.u[3] = r1[1]; pf0[0] = pp.v; }
      a0 = cvtpk(s0[8], s0[9]);   a1 = cvtpk(s0[10], s0[11]);
      b0 = cvtpk(s0[12], s0[13]); b1 = cvtpk(s0[14], s0[15]);
      { auto r0 = __builtin_amdgcn_permlane32_swap(a0, b0, false, false);
        auto r1 = __builtin_amdgcn_permlane32_swap(a1, b1, false, false);
        pp.u[0] = r0[0]; pp.u[1] = r1[0]; pp.u[2] = r0[1]; pp.u[3] = r1[1]; pf0[1] = pp.v; }
      a0 = cvtpk(s1[0], s1[1]);  a1 = cvtpk(s1[2], s1[3]);
      b0 = cvtpk(s1[4], s1[5]);  b1 = cvtpk(s1[6], s1[7]);
      { auto r0 = __builtin_amdgcn_permlane32_swap(a0, b0, false, false);
        auto r1 = __builtin_amdgcn_permlane32_swap(a1, b1, false, false);
        pp.u[0] = r0[0]; pp.u[1] = r1[0]; pp.u[2] = r0[1]; pp.u[3] = r1[1]; pf1[0] = pp.v; }
      a0 = cvtpk(s1[8], s1[9]);   a1 = cvtpk(s1[10], s1[11]);
      b0 = cvtpk(s1[12], s1[13]); b1 = cvtpk(s1[14], s1[15]);
      { auto r0 = __builtin_amdgcn_permlane32_swap(a0, b0, false, false);
        auto r1 = __builtin_amdgcn_permlane32_swap(a1, b1, false, false);
        pp.u[0] = r0[0]; pp.u[1] = r1[0]; pp.u[2] = r0[1]; pp.u[3] = r1[1]; pf1[1] = pp.v; }
    }

    // O^T += V^T * P^T, both chains (independent)
    __builtin_amdgcn_s_setprio(1);
    oA0 = __builtin_amdgcn_mfma_f32_32x32x16_bf16(vA[0], pf0[0], oA0, 0, 0, 0);
    oA1 = __builtin_amdgcn_mfma_f32_32x32x16_bf16(vA[0], pf1[0], oA1, 0, 0, 0);
    oB0 = __builtin_amdgcn_mfma_f32_32x32x16_bf16(vB[0], pf0[0], oB0, 0, 0, 0);
    oB1 = __builtin_amdgcn_mfma_f32_32x32x16_bf16(vB[0], pf1[0], oB1, 0, 0, 0);
    oA0 = __builtin_amdgcn_mfma_f32_32x32x16_bf16(vA[1], pf0[1], oA0, 0, 0, 0);
    oA1 = __builtin_amdgcn_mfma_f32_32x32x16_bf16(vA[1], pf1[1], oA1, 0, 0, 0);
    oB0 = __builtin_amdgcn_mfma_f32_32x32x16_bf16(vB[1], pf0[1], oB0, 0, 0, 0);
    oB1 = __builtin_amdgcn_mfma_f32_32x32x16_bf16(vB[1], pf1[1], oB1, 0, 0, 0);
    __builtin_amdgcn_s_setprio(0);

    // my LDS reads done -> safe to overwrite my own buffer (wave-private, no barrier)
    asm volatile("s_waitcnt lgkmcnt(0)" ::: "memory");
    if (t + 2 < NT) stage(cur, kvb + (t + 2) * 32);
  }

  // ---- merge the two kv-halves through LDS (staging regions are free now) ----
  float* Om = (float*)smem;              // [64 q][64 d] f32 = 16KB
  float* Ml = (float*)(smem + 16384);    // [64 q][2]
  __syncthreads();
  if (wid == 1) {
#pragma unroll
    for (int qc = 0; qc < 2; qc++) {
      int ql = qc * 32 + l31;
      const f32x16& xa = qc ? oA1 : oA0;
      const f32x16& xb = qc ? oB1 : oB0;
      if (h == 0) { Ml[ql * 2] = qc ? m1 : m0; Ml[ql * 2 + 1] = qc ? ls1 : ls0; }
#pragma unroll
      for (int g = 0; g < 4; g++) {
        *reinterpret_cast<float4*>(&Om[ql * 64 + 8 * g + 4 * h]) =
            make_float4(xa[4 * g], xa[4 * g + 1], xa[4 * g + 2], xa[4 * g + 3]);
        *reinterpret_cast<float4*>(&Om[ql * 64 + 32 + 8 * g + 4 * h]) =
            make_float4(xb[4 * g], xb[4 * g + 1], xb[4 * g + 2], xb[4 * g + 3]);
      }
    }
  }
  __syncthreads();
  if (wid == 0) {
#pragma unroll
    for (int qc = 0; qc < 2; qc++) {
      int ql = qc * 32 + l31;
      const f32x16& xa = qc ? oA1 : oA0;
      const f32x16& xb = qc ? oB1 : oB0;
      float mm = qc ? m1 : m0, ll = qc ? ls1 : ls0;
      float mo = Ml[ql * 2], lo = Ml[ql * 2 + 1];
      float M = fmaxf(mm, mo);
      float a0 = exp2f((mm - M) * SC2);
      float a1 = exp2f((mo - M) * SC2);
      float invl = 1.0f / (ll * a0 + lo * a1);
      int n = q0 + ql;
      u16* op = aout + ((size_t)(b * SEQ + n)) * DIM + hh * HDIM;
#pragma unroll
      for (int g = 0; g < 4; g++) {
        float vA[4], vB[4];
#pragma unroll
        for (int i = 0; i < 4; i++) {
          vA[i] = (xa[4 * g + i] * a0 + Om[ql * 64 + 8 * g + 4 * h + i] * a1) * invl;
          vB[i] = (xb[4 * g + i] * a0 + Om[ql * 64 + 32 + 8 * g + 4 * h + i] * a1) * invl;
        }
        *reinterpret_cast<uint2*>(op + 8 * g + 4 * h) =
            make_uint2(pk2(vA[0], vA[1]), pk2(vA[2], vA[3]));
        *reinterpret_cast<uint2*>(op + 32 + 8 * g + 4 * h) =
            make_uint2(pk2(vB[0], vB[1]), pk2(vB[2], vB[3]));
      }
    }
  }
}

// ---------------- launch ----------------
extern "C" void kernel_launch(void* const* d_in, const int* in_sizes, int n_in,
                              void* d_out, int out_size, void* d_ws, size_t ws_size,
                              hipStream_t stream) {
  (void)in_sizes; (void)n_in; (void)out_size; (void)ws_size;
  const float* x      = (const float*)d_in[0];
  const float* qkv_w  = (const float*)d_in[1];
  const float* qkv_b  = (const float*)d_in[2];
  const float* proj_w = (const float*)d_in[3];
  const float* proj_b = (const float*)d_in[4];
  float* out = (float*)d_out;

  char* w = (char*)d_ws;
  u16* xb     = (u16*)w;  w += (size_t)MTOK * DIM * 2;
  u16* wqkvb  = (u16*)w;  w += (size_t)3 * DIM * DIM * 2;
  u16* wprojb = (u16*)w;  w += (size_t)DIM * DIM * 2;
  u16* qb     = (u16*)w;  w += (size_t)BHN * SEQ * HDIM * 2;
  u16* kb     = (u16*)w;  w += (size_t)BHN * SEQ * HDIM * 2;
  u16* vtb    = (u16*)w;  w += (size_t)BHN * SEQ * HDIM * 2;
  u16* aout   = (u16*)w;  w += (size_t)MTOK * DIM * 2;
  float2* tab = (float2*)w;

  k_prep<<<(PREP_E + 255) / 256, 256, 0, stream>>>(
      (const float4*)x, (const float4*)qkv_w, (const float4*)proj_w,
      (ushort4*)xb, (ushort4*)wqkvb, (ushort4*)wprojb, tab);

  k_gemm<1><<<dim3(3 * DIM / 128, MTOK / 128), 256, 0, stream>>>(
      xb, wqkvb, qkv_b, DIM, nullptr, qb, kb, vtb, tab);

  k_attn<<<1024, 128, 0, stream>>>(qb, kb, vtb, aout);

  k_gemm<0><<<dim3(DIM / 128, MTOK / 128), 256, 0, stream>>>(
      aout, wprojb, proj_b, DIM, out, nullptr, nullptr, nullptr, nullptr);
}

// Round 7
// 153.708 us; speedup vs baseline: 1.1358x; 1.0188x over previous
//
#include <hip/hip_runtime.h>
#include <hip/hip_bf16.h>
#include <stdint.h>

#define DIM   1024
#define NH    16
#define HDIM  64
#define SEQ   2048
#define BATCH 2
#define BHN   32            // BATCH*NH
#define MTOK  4096          // BATCH*SEQ
#define SC2   0.18033688f   // (1/sqrt(64)) * log2(e)

using u16 = unsigned short;
using u32 = unsigned int;
typedef __attribute__((ext_vector_type(8))) short short8;   // MFMA A/B frag (8 bf16)
typedef __attribute__((ext_vector_type(4))) float f32x4;    // 16x16 MFMA C/D frag
typedef __attribute__((ext_vector_type(16))) float f32x16;  // 32x32 MFMA C/D frag

__device__ __forceinline__ u16 f2bf(float f) {
  __hip_bfloat16 h = __float2bfloat16(f);
  return *reinterpret_cast<u16*>(&h);
}
__device__ __forceinline__ float bf2f(u16 u) {
  u32 v = ((u32)u) << 16;
  return __builtin_bit_cast(float, v);
}
__device__ __forceinline__ u32 pk2(float lo, float hi) {
  return (u32)f2bf(lo) | ((u32)f2bf(hi) << 16);
}
// hardware packed f32->bf16 (RNE), 1 instr for 2 values
__device__ __forceinline__ u32 cvtpk(float lo, float hi) {
  u32 r;
  asm("v_cvt_pk_bf16_f32 %0, %1, %2" : "=v"(r) : "v"(lo), "v"(hi));
  return r;
}

// async global->LDS, 16B per lane. lds base must be wave-uniform; gsrc per-lane.
__device__ __forceinline__ void gload16(const void* g, void* lds) {
  __builtin_amdgcn_global_load_lds(
      (const __attribute__((address_space(1))) u32*)g,
      (__attribute__((address_space(3))) u32*)lds, 16, 0, 0);
}

// ---------------- fused prep: fp32->bf16 x3 + RoPE cos/sin table ----------------
#define PREP_A 1048576              // x: MTOK*DIM/4
#define PREP_B 1835008              // + qkv_w: 3*DIM*DIM/4
#define PREP_C 2097152              // + proj_w: DIM*DIM/4
#define PREP_E 2162688              // + tab: SEQ*32
__global__ void k_prep(const float4* __restrict__ x, const float4* __restrict__ qw,
                       const float4* __restrict__ pw, ushort4* __restrict__ xb,
                       ushort4* __restrict__ qwb, ushort4* __restrict__ pwb,
                       float2* __restrict__ tab) {
  int i = blockIdx.x * blockDim.x + threadIdx.x;
  if (i < PREP_A) {
    float4 v = x[i];
    xb[i] = make_ushort4(f2bf(v.x), f2bf(v.y), f2bf(v.z), f2bf(v.w));
  } else if (i < PREP_B) {
    int j = i - PREP_A;
    float4 v = qw[j];
    qwb[j] = make_ushort4(f2bf(v.x), f2bf(v.y), f2bf(v.z), f2bf(v.w));
  } else if (i < PREP_C) {
    int j = i - PREP_B;
    float4 v = pw[j];
    pwb[j] = make_ushort4(f2bf(v.x), f2bf(v.y), f2bf(v.z), f2bf(v.w));
  } else if (i < PREP_E) {
    int j = i - PREP_C;
    int n = j >> 5, f = j & 31;
    float inv = powf(10000.f, -(2.f * f) / 64.f);
    float s, c;
    sincosf((float)n * inv, &s, &c);
    tab[j] = make_float2(c, s);
  }
}

// ---------------- bf16 GEMM: C = A * Bt^T, 128x128 tile, BK=64 ----------------
// EPI=0: fp32 out + bias (proj). EPI=1: bias + fused RoPE + bf16 scatter to q/k/vt.
template <int EPI>
__global__ __launch_bounds__(256, 2) void k_gemm(
    const u16* __restrict__ A, const u16* __restrict__ Bt,
    const float* __restrict__ bias, int K,
    float* __restrict__ out_f, u16* __restrict__ qb, u16* __restrict__ kb,
    u16* __restrict__ vtb, const float2* __restrict__ tab) {
  __shared__ u16 As[128 * 64];
  __shared__ u16 Bs[128 * 64];
  const int tid = threadIdx.x;
  const int wid = tid >> 6, lane = tid & 63;
  const int lq = lane & 15, g = lane >> 4;
  const int wr = wid >> 1, wc = wid & 1;
  const int brow = blockIdx.y * 128;
  const int bcol = blockIdx.x * 128;
  f32x4 acc[4][4] = {};
  const u16* Ab = A + (size_t)brow * K;
  const u16* Bb = Bt + (size_t)bcol * K;

  for (int k0 = 0; k0 < K; k0 += 64) {
#pragma unroll
    for (int t = 0; t < 4; t++) {
      int rl = wid * 32 + t * 8 + (lane >> 3);
      int cs = (lane & 7) ^ (rl & 7);
      gload16(Ab + (size_t)rl * K + k0 + cs * 8, &As[(wid * 32 + t * 8) * 64]);
      gload16(Bb + (size_t)rl * K + k0 + cs * 8, &Bs[(wid * 32 + t * 8) * 64]);
    }
    __syncthreads();
#pragma unroll
    for (int kc = 0; kc < 2; kc++) {
      short8 af[4], bfr[4];
#pragma unroll
      for (int mt = 0; mt < 4; mt++) {
        int r = wr * 64 + mt * 16 + lq;
        af[mt] = *reinterpret_cast<const short8*>(&As[r * 64 + (((kc * 4 + g) ^ (r & 7)) * 8)]);
      }
#pragma unroll
      for (int nt = 0; nt < 4; nt++) {
        int r = wc * 64 + nt * 16 + lq;
        bfr[nt] = *reinterpret_cast<const short8*>(&Bs[r * 64 + (((kc * 4 + g) ^ (r & 7)) * 8)]);
      }
#pragma unroll
      for (int mt = 0; mt < 4; mt++)
#pragma unroll
        for (int nt = 0; nt < 4; nt++)
          acc[mt][nt] = __builtin_amdgcn_mfma_f32_16x16x32_bf16(af[mt], bfr[nt], acc[mt][nt], 0, 0, 0);
    }
    __syncthreads();
  }

#pragma unroll
  for (int mt = 0; mt < 4; mt++) {
    int row0 = brow + wr * 64 + mt * 16 + g * 4;
#pragma unroll
    for (int nt = 0; nt < 4; nt++) {
      int col = bcol + wc * 64 + nt * 16 + lq;
      float bv = bias[col];
      float v[4];
#pragma unroll
      for (int r = 0; r < 4; r++) v[r] = acc[mt][nt][r] + bv;
      if (EPI == 0) {
#pragma unroll
        for (int r = 0; r < 4; r++) out_f[(size_t)(row0 + r) * DIM + col] = v[r];
      } else {
        int which = col >> 10, hd = col & 1023, hdh = hd >> 6, d = hd & 63;
        int bb = row0 >> 11, n0 = row0 & 2047;
        if (which == 2) {
          // V^T store: 4 r-values are consecutive n -> one 8B store (coalesced granule)
          uint2 pv = make_uint2(pk2(v[0], v[1]), pk2(v[2], v[3]));
          *reinterpret_cast<uint2*>(&vtb[(((size_t)bb * NH + hdh) * HDIM + d) * SEQ + n0]) = pv;
        } else {
#pragma unroll
          for (int r = 0; r < 4; r++) {
            int n = n0 + r;
            // fused RoPE: partner value (col^1) lives in adjacent lane
            float p = __shfl_xor(v[r], 1);
            float2 cs = tab[n * 32 + (d >> 1)];
            float vv = (d & 1) ? fmaf(p, cs.y, v[r] * cs.x)   // o' = e*s + o*c
                               : fmaf(-p, cs.y, v[r] * cs.x); // e' = e*c - o*s
            u16 xo = f2bf(vv);
            if (which == 0) qb[(((size_t)bb * NH + hdh) * SEQ + n) * HDIM + d] = xo;
            else            kb[(((size_t)bb * NH + hdh) * SEQ + n) * HDIM + d] = xo;
          }
        }
      }
    }
  }
}

// ---------------- flash attention: R4 pipeline, 2-wave blocks ----------------
// grid 1024 (XCD-swizzled: 4 heads/XCD), 128 thr = 2 waves. Block owns 64 q-rows
// (wave w: rows w*32..); both waves share one 64-kv double-buffered K/V stream.
// Counted s_waitcnt vmcnt(8) (8 gloads/stage/wave), raw 2-wave barriers.
// S^T = K*Q^T (32x32x16), per-lane online softmax, cvt_pk+permlane32_swap pack,
// O^T = V^T*P^T. Defer-max rescale.
__global__ __launch_bounds__(128, 2) void k_attn(
    const u16* __restrict__ qg, const u16* __restrict__ kg,
    const u16* __restrict__ vg, u16* __restrict__ aout) {
  __shared__ __align__(16) char smem[32768];   // 2 buf x [K 8KB | V 8KB]
  const int tid = threadIdx.x;
  const int wid = tid >> 6, lane = tid & 63;
  const int l31 = lane & 31, h = lane >> 5;

  // XCD-aware decode: bid&7 = XCD; 4 consecutive heads per XCD (2MB KV / XCD-L2)
  const int bid = blockIdx.x;
  const int xcd = bid & 7, slot = bid >> 3;      // slot 0..127
  const int bh = xcd * 4 + (slot >> 5);
  const int qt = slot & 31;
  const int b = bh >> 4, hh = bh & 15;
  const int q0 = qt * 64 + wid * 32;             // this wave's 32 q-rows

  const u16* kbase = kg + (size_t)bh * SEQ * HDIM;
  const u16* vbase = vg + (size_t)bh * HDIM * SEQ;

  // Q B-frags: chunk c -> d = c*16 + h*8 + j
  const u16* qrow = qg + ((size_t)bh * SEQ + q0 + l31) * HDIM;
  short8 qf[4];
#pragma unroll
  for (int c = 0; c < 4; c++)
    qf[c] = *reinterpret_cast<const short8*>(qrow + c * 16 + h * 8);

  // hoisted swizzled LDS byte-offsets (row l31; +4096 for rows 32-63)
  int koff[4];
#pragma unroll
  for (int c = 0; c < 4; c++)
    koff[c] = l31 * 128 + (((2 * c + h) ^ (l31 & 7)) << 4);

  f32x16 oA = {}, oB = {};
  float m = -INFINITY, lsum = 0.f;

  // stage one 64-kv tile (K 64x128B, V 64x128B); wave w covers 8 rows per round.
  auto stage = [&](int buf, int kv0) {           // 8 gloads/lane
    char* kd = smem + buf * 16384;
#pragma unroll
    for (int i = 0; i < 4; i++) {
      int row = i * 16 + wid * 8 + (lane >> 3);
      int cs = (lane & 7) ^ (row & 7);           // pre-swizzled global source
      gload16(kbase + (size_t)(kv0 + row) * HDIM + cs * 8, kd + i * 2048 + wid * 1024);
      gload16(vbase + (size_t)row * SEQ + kv0 + cs * 8, kd + 8192 + i * 2048 + wid * 1024);
    }
  };

  stage(0, 0);
  stage(1, 64);

  const int NT = SEQ / 64;
  for (int t = 0; t < NT; ++t) {
    const int cur = t & 1;
    if (t < NT - 1) asm volatile("s_waitcnt vmcnt(8)" ::: "memory");
    else            asm volatile("s_waitcnt vmcnt(0)" ::: "memory");
    __builtin_amdgcn_s_barrier();

    const char* kbp = smem + cur * 16384;
    const char* vbp = kbp + 8192;

    // S^T = K * Q^T : s0 = kv 0..31 of tile, s1 = kv 32..63; lane col q = l31
    f32x16 s0 = {}, s1 = {};
    __builtin_amdgcn_s_setprio(1);
#pragma unroll
    for (int c = 0; c < 4; c++) {
      short8 k0 = *reinterpret_cast<const short8*>(kbp + koff[c]);
      short8 k1 = *reinterpret_cast<const short8*>(kbp + koff[c] + 4096);
      s0 = __builtin_amdgcn_mfma_f32_32x32x16_bf16(k0, qf[c], s0, 0, 0, 0);
      s1 = __builtin_amdgcn_mfma_f32_32x32x16_bf16(k1, qf[c], s1, 0, 0, 0);
    }
    __builtin_amdgcn_s_setprio(0);

    // V A-frags issued early: LDS latency hides under softmax VALU
    short8 vf0[4], vf1[4];
#pragma unroll
    for (int c = 0; c < 4; c++) {
      vf0[c] = *reinterpret_cast<const short8*>(vbp + koff[c]);
      vf1[c] = *reinterpret_cast<const short8*>(vbp + koff[c] + 4096);
    }

    // online softmax; lane owns q = l31 (paired across lane^32)
    float tm[8];
#pragma unroll
    for (int r = 0; r < 8; r++)
      tm[r] = fmaxf(fmaxf(s0[r], s1[r]), fmaxf(s0[r + 8], s1[r + 8]));
    float ta = fmaxf(fmaxf(tm[0], tm[1]), tm[2]);
    float tb = fmaxf(fmaxf(tm[3], tm[4]), tm[5]);
    float tc = fmaxf(tm[6], tm[7]);
    float tmax = fmaxf(fmaxf(ta, tb), tc);
    tmax = fmaxf(tmax, __shfl_xor(tmax, 32));

    float alpha = 1.f;
    if (__any(tmax - m > 61.0f)) {     // defer-max: p bounded by 2^11
      float mnew = fmaxf(m, tmax);
      alpha = exp2f((m - mnew) * SC2);
      m = mnew;
#pragma unroll
      for (int r = 0; r < 16; r++) { oA[r] *= alpha; oB[r] *= alpha; }
    }
    const float nms = -m * SC2;
#pragma unroll
    for (int r = 0; r < 16; r++) s0[r] = exp2f(fmaf(s0[r], SC2, nms));
#pragma unroll
    for (int r = 0; r < 16; r++) s1[r] = exp2f(fmaf(s1[r], SC2, nms));
    float pa = 0.f, pb = 0.f, pc = 0.f, pd = 0.f;
#pragma unroll
    for (int r = 0; r < 4; r++) {
      pa += s0[r] + s0[r + 4];
      pb += s0[r + 8] + s0[r + 12];
      pc += s1[r] + s1[r + 4];
      pd += s1[r + 8] + s1[r + 12];
    }
    float psum = (pa + pb) + (pc + pd);
    psum += __shfl_xor(psum, 32);
    lsum = lsum * alpha + psum;

    // pack P to bf16 B-frags: 4 cvt_pk + 2 permlane32_swap per chunk (T12)
    short8 pf[4];
    {
      union { u32 u[4]; short8 v; } pp;
      u32 a0, a1, b0, b1;
      a0 = cvtpk(s0[0], s0[1]);  a1 = cvtpk(s0[2], s0[3]);
      b0 = cvtpk(s0[4], s0[5]);  b1 = cvtpk(s0[6], s0[7]);
      { auto r0 = __builtin_amdgcn_permlane32_swap(a0, b0, false, false);
        auto r1 = __builtin_amdgcn_permlane32_swap(a1, b1, false, false);
        pp.u[0] = r0[0]; pp.u[1] = r1[0]; pp.u[2] = r0[1]; pp.u[3] = r1[1]; pf[0] = pp.v; }
      a0 = cvtpk(s0[8], s0[9]);   a1 = cvtpk(s0[10], s0[11]);
      b0 = cvtpk(s0[12], s0[13]); b1 = cvtpk(s0[14], s0[15]);
      { auto r0 = __builtin_amdgcn_permlane32_swap(a0, b0, false, false);
        auto r1 = __builtin_amdgcn_permlane32_swap(a1, b1, false, false);
        pp.u[0] = r0[0]; pp.u[1] = r1[0]; pp.u[2] = r0[1]; pp.u[3] = r1[1]; pf[1] = pp.v; }
      a0 = cvtpk(s1[0], s1[1]);  a1 = cvtpk(s1[2], s1[3]);
      b0 = cvtpk(s1[4], s1[5]);  b1 = cvtpk(s1[6], s1[7]);
      { auto r0 = __builtin_amdgcn_permlane32_swap(a0, b0, false, false);
        auto r1 = __builtin_amdgcn_permlane32_swap(a1, b1, false, false);
        pp.u[0] = r0[0]; pp.u[1] = r1[0]; pp.u[2] = r0[1]; pp.u[3] = r1[1]; pf[2] = pp.v; }
      a0 = cvtpk(s1[8], s1[9]);   a1 = cvtpk(s1[10], s1[11]);
      b0 = cvtpk(s1[12], s1[13]); b1 = cvtpk(s1[14], s1[15]);
      { auto r0 = __builtin_amdgcn_permlane32_swap(a0, b0, false, false);
        auto r1 = __builtin_amdgcn_permlane32_swap(a1, b1, false, false);
        pp.u[0] = r0[0]; pp.u[1] = r1[0]; pp.u[2] = r0[1]; pp.u[3] = r1[1]; pf[3] = pp.v; }
    }

    // O^T += V^T * P^T : oA = d 0..31, oB = d 32..63; lane col q = l31
    __builtin_amdgcn_s_setprio(1);
#pragma unroll
    for (int c = 0; c < 4; c++) {
      oA = __builtin_amdgcn_mfma_f32_32x32x16_bf16(vf0[c], pf[c], oA, 0, 0, 0);
      oB = __builtin_amdgcn_mfma_f32_32x32x16_bf16(vf1[c], pf[c], oB, 0, 0, 0);
    }
    __builtin_amdgcn_s_setprio(0);

    // all my LDS reads complete -> safe for others to overwrite after barrier
    asm volatile("s_waitcnt lgkmcnt(0)" ::: "memory");
    __builtin_amdgcn_s_barrier();
    if (t + 2 < NT) stage(cur, (t + 2) * 64);   // refill the freed buffer
  }

  // epilogue: d = {0,32} + 8g + 4h + i ; n = q0 + l31
  float invl = 1.0f / lsum;
  int n = q0 + l31;
  u16* op = aout + ((size_t)(b * SEQ + n)) * DIM + hh * HDIM;
#pragma unroll
  for (int g = 0; g < 4; g++) {
    u32 w0 = pk2(oA[4 * g] * invl, oA[4 * g + 1] * invl);
    u32 w1 = pk2(oA[4 * g + 2] * invl, oA[4 * g + 3] * invl);
    *reinterpret_cast<uint2*>(op + 8 * g + 4 * h) = make_uint2(w0, w1);
    u32 x0 = pk2(oB[4 * g] * invl, oB[4 * g + 1] * invl);
    u32 x1 = pk2(oB[4 * g + 2] * invl, oB[4 * g + 3] * invl);
    *reinterpret_cast<uint2*>(op + 32 + 8 * g + 4 * h) = make_uint2(x0, x1);
  }
}

// ---------------- launch ----------------
extern "C" void kernel_launch(void* const* d_in, const int* in_sizes, int n_in,
                              void* d_out, int out_size, void* d_ws, size_t ws_size,
                              hipStream_t stream) {
  (void)in_sizes; (void)n_in; (void)out_size; (void)ws_size;
  const float* x      = (const float*)d_in[0];
  const float* qkv_w  = (const float*)d_in[1];
  const float* qkv_b  = (const float*)d_in[2];
  const float* proj_w = (const float*)d_in[3];
  const float* proj_b = (const float*)d_in[4];
  float* out = (float*)d_out;

  char* w = (char*)d_ws;
  u16* xb     = (u16*)w;  w += (size_t)MTOK * DIM * 2;
  u16* wqkvb  = (u16*)w;  w += (size_t)3 * DIM * DIM * 2;
  u16* wprojb = (u16*)w;  w += (size_t)DIM * DIM * 2;
  u16* qb     = (u16*)w;  w += (size_t)BHN * SEQ * HDIM * 2;
  u16* kb     = (u16*)w;  w += (size_t)BHN * SEQ * HDIM * 2;
  u16* vtb    = (u16*)w;  w += (size_t)BHN * SEQ * HDIM * 2;
  u16* aout   = (u16*)w;  w += (size_t)MTOK * DIM * 2;
  float2* tab = (float2*)w;

  k_prep<<<(PREP_E + 255) / 256, 256, 0, stream>>>(
      (const float4*)x, (const float4*)qkv_w, (const float4*)proj_w,
      (ushort4*)xb, (ushort4*)wqkvb, (ushort4*)wprojb, tab);

  k_gemm<1><<<dim3(3 * DIM / 128, MTOK / 128), 256, 0, stream>>>(
      xb, wqkvb, qkv_b, DIM, nullptr, qb, kb, vtb, tab);

  k_attn<<<1024, 128, 0, stream>>>(qb, kb, vtb, aout);

  k_gemm<0><<<dim3(DIM / 128, MTOK / 128), 256, 0, stream>>>(
      aout, wprojb, proj_b, DIM, out, nullptr, nullptr, nullptr, nullptr);
}

// Round 8
// 135.162 us; speedup vs baseline: 1.2916x; 1.1372x over previous
//
#include <hip/hip_runtime.h>
#include <hip/hip_bf16.h>
#include <stdint.h>

#define DIM   1024
#define NH    16
#define HDIM  64
#define SEQ   2048
#define BATCH 2
#define BHN   32            // BATCH*NH
#define MTOK  4096          // BATCH*SEQ
#define SC2   0.18033688f   // (1/sqrt(64)) * log2(e)

using u16 = unsigned short;
using u32 = unsigned int;
typedef __attribute__((ext_vector_type(8))) short short8;   // MFMA A/B frag (8 bf16)
typedef __attribute__((ext_vector_type(4))) float f32x4;    // 16x16 MFMA C/D frag
typedef __attribute__((ext_vector_type(16))) float f32x16;  // 32x32 MFMA C/D frag

__device__ __forceinline__ u16 f2bf(float f) {
  __hip_bfloat16 h = __float2bfloat16(f);
  return *reinterpret_cast<u16*>(&h);
}
__device__ __forceinline__ float bf2f(u16 u) {
  u32 v = ((u32)u) << 16;
  return __builtin_bit_cast(float, v);
}
__device__ __forceinline__ u32 pk2(float lo, float hi) {
  return (u32)f2bf(lo) | ((u32)f2bf(hi) << 16);
}
// hardware packed f32->bf16 (RNE), 1 instr for 2 values
__device__ __forceinline__ u32 cvtpk(float lo, float hi) {
  u32 r;
  asm("v_cvt_pk_bf16_f32 %0, %1, %2" : "=v"(r) : "v"(lo), "v"(hi));
  return r;
}

// async global->LDS, 16B per lane. lds base must be wave-uniform; gsrc per-lane.
__device__ __forceinline__ void gload16(const void* g, void* lds) {
  __builtin_amdgcn_global_load_lds(
      (const __attribute__((address_space(1))) u32*)g,
      (__attribute__((address_space(3))) u32*)lds, 16, 0, 0);
}

// ---------------- fused prep: fp32->bf16 x3 + RoPE cos/sin table ----------------
#define PREP_A 1048576              // x: MTOK*DIM/4
#define PREP_B 1835008              // + qkv_w: 3*DIM*DIM/4
#define PREP_C 2097152              // + proj_w: DIM*DIM/4
#define PREP_E 2162688              // + tab: SEQ*32
__global__ void k_prep(const float4* __restrict__ x, const float4* __restrict__ qw,
                       const float4* __restrict__ pw, ushort4* __restrict__ xb,
                       ushort4* __restrict__ qwb, ushort4* __restrict__ pwb,
                       float2* __restrict__ tab) {
  int i = blockIdx.x * blockDim.x + threadIdx.x;
  if (i < PREP_A) {
    float4 v = x[i];
    xb[i] = make_ushort4(f2bf(v.x), f2bf(v.y), f2bf(v.z), f2bf(v.w));
  } else if (i < PREP_B) {
    int j = i - PREP_A;
    float4 v = qw[j];
    qwb[j] = make_ushort4(f2bf(v.x), f2bf(v.y), f2bf(v.z), f2bf(v.w));
  } else if (i < PREP_C) {
    int j = i - PREP_B;
    float4 v = pw[j];
    pwb[j] = make_ushort4(f2bf(v.x), f2bf(v.y), f2bf(v.z), f2bf(v.w));
  } else if (i < PREP_E) {
    int j = i - PREP_C;
    int n = j >> 5, f = j & 31;
    float inv = powf(10000.f, -(2.f * f) / 64.f);
    float s, c;
    sincosf((float)n * inv, &s, &c);
    tab[j] = make_float2(c, s);
  }
}

// ---------------- bf16 GEMM: C = A * Bt^T, 128x128 tile, BK=64 ----------------
// EPI=0: fp32 out + bias (proj). EPI=1: bias + fused RoPE + bf16 scatter to q/k/vt.
template <int EPI>
__global__ __launch_bounds__(256, 2) void k_gemm(
    const u16* __restrict__ A, const u16* __restrict__ Bt,
    const float* __restrict__ bias, int K,
    float* __restrict__ out_f, u16* __restrict__ qb, u16* __restrict__ kb,
    u16* __restrict__ vtb, const float2* __restrict__ tab) {
  __shared__ u16 As[128 * 64];
  __shared__ u16 Bs[128 * 64];
  const int tid = threadIdx.x;
  const int wid = tid >> 6, lane = tid & 63;
  const int lq = lane & 15, g = lane >> 4;
  const int wr = wid >> 1, wc = wid & 1;
  const int brow = blockIdx.y * 128;
  const int bcol = blockIdx.x * 128;
  f32x4 acc[4][4] = {};
  const u16* Ab = A + (size_t)brow * K;
  const u16* Bb = Bt + (size_t)bcol * K;

  for (int k0 = 0; k0 < K; k0 += 64) {
#pragma unroll
    for (int t = 0; t < 4; t++) {
      int rl = wid * 32 + t * 8 + (lane >> 3);
      int cs = (lane & 7) ^ (rl & 7);
      gload16(Ab + (size_t)rl * K + k0 + cs * 8, &As[(wid * 32 + t * 8) * 64]);
      gload16(Bb + (size_t)rl * K + k0 + cs * 8, &Bs[(wid * 32 + t * 8) * 64]);
    }
    __syncthreads();
#pragma unroll
    for (int kc = 0; kc < 2; kc++) {
      short8 af[4], bfr[4];
#pragma unroll
      for (int mt = 0; mt < 4; mt++) {
        int r = wr * 64 + mt * 16 + lq;
        af[mt] = *reinterpret_cast<const short8*>(&As[r * 64 + (((kc * 4 + g) ^ (r & 7)) * 8)]);
      }
#pragma unroll
      for (int nt = 0; nt < 4; nt++) {
        int r = wc * 64 + nt * 16 + lq;
        bfr[nt] = *reinterpret_cast<const short8*>(&Bs[r * 64 + (((kc * 4 + g) ^ (r & 7)) * 8)]);
      }
#pragma unroll
      for (int mt = 0; mt < 4; mt++)
#pragma unroll
        for (int nt = 0; nt < 4; nt++)
          acc[mt][nt] = __builtin_amdgcn_mfma_f32_16x16x32_bf16(af[mt], bfr[nt], acc[mt][nt], 0, 0, 0);
    }
    __syncthreads();
  }

#pragma unroll
  for (int mt = 0; mt < 4; mt++) {
    int row0 = brow + wr * 64 + mt * 16 + g * 4;
#pragma unroll
    for (int nt = 0; nt < 4; nt++) {
      int col = bcol + wc * 64 + nt * 16 + lq;
      float bv = bias[col];
      float v[4];
#pragma unroll
      for (int r = 0; r < 4; r++) v[r] = acc[mt][nt][r] + bv;
      if (EPI == 0) {
#pragma unroll
        for (int r = 0; r < 4; r++) out_f[(size_t)(row0 + r) * DIM + col] = v[r];
      } else {
        int which = col >> 10, hd = col & 1023, hdh = hd >> 6, d = hd & 63;
        int bb = row0 >> 11, n0 = row0 & 2047;
        if (which == 2) {
          // V^T store: 4 r-values are consecutive n -> one 8B store (coalesced granule)
          uint2 pv = make_uint2(pk2(v[0], v[1]), pk2(v[2], v[3]));
          *reinterpret_cast<uint2*>(&vtb[(((size_t)bb * NH + hdh) * HDIM + d) * SEQ + n0]) = pv;
        } else {
#pragma unroll
          for (int r = 0; r < 4; r++) {
            int n = n0 + r;
            // fused RoPE: partner value (col^1) lives in adjacent lane
            float p = __shfl_xor(v[r], 1);
            float2 cs = tab[n * 32 + (d >> 1)];
            float vv = (d & 1) ? fmaf(p, cs.y, v[r] * cs.x)   // o' = e*s + o*c
                               : fmaf(-p, cs.y, v[r] * cs.x); // e' = e*c - o*s
            u16 xo = f2bf(vv);
            if (which == 0) qb[(((size_t)bb * NH + hdh) * SEQ + n) * HDIM + d] = xo;
            else            kb[(((size_t)bb * NH + hdh) * SEQ + n) * HDIM + d] = xo;
          }
        }
      }
    }
  }
}

// ---------------- flash attention: R4 structure + 3-buffer single-barrier pipeline ----------------
// grid 512 (XCD-swizzled: 4 heads/XCD), 256 thr = 4 waves x 32 q-rows; shared 64-kv
// stream in 3 rotating LDS buffers (48KB). ONE barrier per tile: stage at iter t
// targets buf[(t+2)%3]; reads of that buffer (iter t-1) completed before barrier t.
// Counted s_waitcnt vmcnt(4); no lgkmcnt drain, no second barrier.
// S^T = K*Q^T (32x32x16), per-lane online softmax, cvt_pk+permlane32_swap pack,
// O^T = V^T*P^T. Defer-max rescale.
__global__ __launch_bounds__(256, 2) void k_attn(
    const u16* __restrict__ qg, const u16* __restrict__ kg,
    const u16* __restrict__ vg, u16* __restrict__ aout) {
  __shared__ __align__(16) char smem[49152];   // 3 buf x [K 8KB | V 8KB]
  const int tid = threadIdx.x;
  const int wid = tid >> 6, lane = tid & 63;
  const int l31 = lane & 31, h = lane >> 5;

  // XCD-aware decode: bid&7 = XCD; 4 consecutive heads per XCD (2MB KV / XCD-L2)
  const int bid = blockIdx.x;
  const int xcd = bid & 7, slot = bid >> 3;      // slot 0..63
  const int bh = xcd * 4 + (slot >> 4);
  const int qt = slot & 15;
  const int b = bh >> 4, hh = bh & 15;
  const int q0 = qt * 128 + wid * 32;            // this wave's 32 q-rows

  const u16* kbase = kg + (size_t)bh * SEQ * HDIM;
  const u16* vbase = vg + (size_t)bh * HDIM * SEQ;

  // Q B-frags: chunk c -> d = c*16 + h*8 + j
  const u16* qrow = qg + ((size_t)bh * SEQ + q0 + l31) * HDIM;
  short8 qf[4];
#pragma unroll
  for (int c = 0; c < 4; c++)
    qf[c] = *reinterpret_cast<const short8*>(qrow + c * 16 + h * 8);

  // hoisted swizzled LDS byte-offsets (row l31; +4096 for rows 32-63)
  int koff[4];
#pragma unroll
  for (int c = 0; c < 4; c++)
    koff[c] = l31 * 128 + (((2 * c + h) ^ (l31 & 7)) << 4);

  f32x16 oA = {}, oB = {};
  float m = -INFINITY, lsum = 0.f;

  // stage one 64-kv tile (K 64 rows x 128B, V 64 rows x 128B); 4 gloads/lane.
  auto stage = [&](int buf, int kv0) {
    char* kd = smem + buf * 16384;
#pragma unroll
    for (int t = 0; t < 2; t++) {
      int rl = wid * 16 + t * 8 + (lane >> 3);
      int cs = (lane & 7) ^ (rl & 7);            // pre-swizzled global source
      gload16(kbase + (size_t)(kv0 + rl) * HDIM + cs * 8, kd + (wid * 16 + t * 8) * 128);
      gload16(vbase + (size_t)rl * SEQ + kv0 + cs * 8, kd + 8192 + (wid * 16 + t * 8) * 128);
    }
  };

  stage(0, 0);
  stage(1, 64);

  const int NT = SEQ / 64;
  int cur = 0, nxt = 2;                          // buf index of tile t, and of tile t+2
  for (int t = 0; t < NT; ++t) {
    if (t < NT - 1) asm volatile("s_waitcnt vmcnt(4)" ::: "memory");
    else            asm volatile("s_waitcnt vmcnt(0)" ::: "memory");
    __builtin_amdgcn_s_barrier();                // tile t ready for everyone

    const char* kbp = smem + cur * 16384;
    const char* vbp = kbp + 8192;

    // S^T = K * Q^T : s0 = kv 0..31 of tile, s1 = kv 32..63; lane col q = l31
    f32x16 s0 = {}, s1 = {};
    __builtin_amdgcn_s_setprio(1);
#pragma unroll
    for (int c = 0; c < 4; c++) {
      short8 k0 = *reinterpret_cast<const short8*>(kbp + koff[c]);
      short8 k1 = *reinterpret_cast<const short8*>(kbp + koff[c] + 4096);
      s0 = __builtin_amdgcn_mfma_f32_32x32x16_bf16(k0, qf[c], s0, 0, 0, 0);
      s1 = __builtin_amdgcn_mfma_f32_32x32x16_bf16(k1, qf[c], s1, 0, 0, 0);
    }
    __builtin_amdgcn_s_setprio(0);

    // V A-frags issued early: LDS latency hides under softmax VALU
    short8 vf0[4], vf1[4];
#pragma unroll
    for (int c = 0; c < 4; c++) {
      vf0[c] = *reinterpret_cast<const short8*>(vbp + koff[c]);
      vf1[c] = *reinterpret_cast<const short8*>(vbp + koff[c] + 4096);
    }

    // prefetch tile t+2 into the buffer consumed at iter t-1 (safe: barrier t
    // ordered everyone's t-1 reads before this write)
    if (t + 2 < NT) stage(nxt, (t + 2) * 64);

    // online softmax; lane owns q = l31 (paired across lane^32)
    float tm[8];
#pragma unroll
    for (int r = 0; r < 8; r++)
      tm[r] = fmaxf(fmaxf(s0[r], s1[r]), fmaxf(s0[r + 8], s1[r + 8]));
    float ta = fmaxf(fmaxf(tm[0], tm[1]), tm[2]);
    float tb = fmaxf(fmaxf(tm[3], tm[4]), tm[5]);
    float tc = fmaxf(tm[6], tm[7]);
    float tmax = fmaxf(fmaxf(ta, tb), tc);
    tmax = fmaxf(tmax, __shfl_xor(tmax, 32));

    float alpha = 1.f;
    if (__any(tmax - m > 61.0f)) {     // defer-max: p bounded by 2^11
      float mnew = fmaxf(m, tmax);
      alpha = exp2f((m - mnew) * SC2);
      m = mnew;
#pragma unroll
      for (int r = 0; r < 16; r++) { oA[r] *= alpha; oB[r] *= alpha; }
    }
    const float nms = -m * SC2;
#pragma unroll
    for (int r = 0; r < 16; r++) s0[r] = exp2f(fmaf(s0[r], SC2, nms));
#pragma unroll
    for (int r = 0; r < 16; r++) s1[r] = exp2f(fmaf(s1[r], SC2, nms));
    float pa = 0.f, pb = 0.f, pc = 0.f, pd = 0.f;
#pragma unroll
    for (int r = 0; r < 4; r++) {
      pa += s0[r] + s0[r + 4];
      pb += s0[r + 8] + s0[r + 12];
      pc += s1[r] + s1[r + 4];
      pd += s1[r + 8] + s1[r + 12];
    }
    float psum = (pa + pb) + (pc + pd);
    psum += __shfl_xor(psum, 32);
    lsum = lsum * alpha + psum;

    // pack P to bf16 B-frags: 4 cvt_pk + 2 permlane32_swap per chunk (T12)
    short8 pf[4];
    {
      union { u32 u[4]; short8 v; } pp;
      u32 a0, a1, b0, b1;
      a0 = cvtpk(s0[0], s0[1]);  a1 = cvtpk(s0[2], s0[3]);
      b0 = cvtpk(s0[4], s0[5]);  b1 = cvtpk(s0[6], s0[7]);
      { auto r0 = __builtin_amdgcn_permlane32_swap(a0, b0, false, false);
        auto r1 = __builtin_amdgcn_permlane32_swap(a1, b1, false, false);
        pp.u[0] = r0[0]; pp.u[1] = r1[0]; pp.u[2] = r0[1]; pp.u[3] = r1[1]; pf[0] = pp.v; }
      a0 = cvtpk(s0[8], s0[9]);   a1 = cvtpk(s0[10], s0[11]);
      b0 = cvtpk(s0[12], s0[13]); b1 = cvtpk(s0[14], s0[15]);
      { auto r0 = __builtin_amdgcn_permlane32_swap(a0, b0, false, false);
        auto r1 = __builtin_amdgcn_permlane32_swap(a1, b1, false, false);
        pp.u[0] = r0[0]; pp.u[1] = r1[0]; pp.u[2] = r0[1]; pp.u[3] = r1[1]; pf[1] = pp.v; }
      a0 = cvtpk(s1[0], s1[1]);  a1 = cvtpk(s1[2], s1[3]);
      b0 = cvtpk(s1[4], s1[5]);  b1 = cvtpk(s1[6], s1[7]);
      { auto r0 = __builtin_amdgcn_permlane32_swap(a0, b0, false, false);
        auto r1 = __builtin_amdgcn_permlane32_swap(a1, b1, false, false);
        pp.u[0] = r0[0]; pp.u[1] = r1[0]; pp.u[2] = r0[1]; pp.u[3] = r1[1]; pf[2] = pp.v; }
      a0 = cvtpk(s1[8], s1[9]);   a1 = cvtpk(s1[10], s1[11]);
      b0 = cvtpk(s1[12], s1[13]); b1 = cvtpk(s1[14], s1[15]);
      { auto r0 = __builtin_amdgcn_permlane32_swap(a0, b0, false, false);
        auto r1 = __builtin_amdgcn_permlane32_swap(a1, b1, false, false);
        pp.u[0] = r0[0]; pp.u[1] = r1[0]; pp.u[2] = r0[1]; pp.u[3] = r1[1]; pf[3] = pp.v; }
    }

    // O^T += V^T * P^T : oA = d 0..31, oB = d 32..63; lane col q = l31
    __builtin_amdgcn_s_setprio(1);
#pragma unroll
    for (int c = 0; c < 4; c++) {
      oA = __builtin_amdgcn_mfma_f32_32x32x16_bf16(vf0[c], pf[c], oA, 0, 0, 0);
      oB = __builtin_amdgcn_mfma_f32_32x32x16_bf16(vf1[c], pf[c], oB, 0, 0, 0);
    }
    __builtin_amdgcn_s_setprio(0);

    cur = cur == 2 ? 0 : cur + 1;
    nxt = nxt == 2 ? 0 : nxt + 1;
  }

  // epilogue: d = {0,32} + 8g + 4h + i ; n = q0 + l31
  float invl = 1.0f / lsum;
  int n = q0 + l31;
  u16* op = aout + ((size_t)(b * SEQ + n)) * DIM + hh * HDIM;
#pragma unroll
  for (int g = 0; g < 4; g++) {
    u32 w0 = pk2(oA[4 * g] * invl, oA[4 * g + 1] * invl);
    u32 w1 = pk2(oA[4 * g + 2] * invl, oA[4 * g + 3] * invl);
    *reinterpret_cast<uint2*>(op + 8 * g + 4 * h) = make_uint2(w0, w1);
    u32 x0 = pk2(oB[4 * g] * invl, oB[4 * g + 1] * invl);
    u32 x1 = pk2(oB[4 * g + 2] * invl, oB[4 * g + 3] * invl);
    *reinterpret_cast<uint2*>(op + 32 + 8 * g + 4 * h) = make_uint2(x0, x1);
  }
}

// ---------------- launch ----------------
extern "C" void kernel_launch(void* const* d_in, const int* in_sizes, int n_in,
                              void* d_out, int out_size, void* d_ws, size_t ws_size,
                              hipStream_t stream) {
  (void)in_sizes; (void)n_in; (void)out_size; (void)ws_size;
  const float* x      = (const float*)d_in[0];
  const float* qkv_w  = (const float*)d_in[1];
  const float* qkv_b  = (const float*)d_in[2];
  const float* proj_w = (const float*)d_in[3];
  const float* proj_b = (const float*)d_in[4];
  float* out = (float*)d_out;

  char* w = (char*)d_ws;
  u16* xb     = (u16*)w;  w += (size_t)MTOK * DIM * 2;
  u16* wqkvb  = (u16*)w;  w += (size_t)3 * DIM * DIM * 2;
  u16* wprojb = (u16*)w;  w += (size_t)DIM * DIM * 2;
  u16* qb     = (u16*)w;  w += (size_t)BHN * SEQ * HDIM * 2;
  u16* kb     = (u16*)w;  w += (size_t)BHN * SEQ * HDIM * 2;
  u16* vtb    = (u16*)w;  w += (size_t)BHN * SEQ * HDIM * 2;
  u16* aout   = (u16*)w;  w += (size_t)MTOK * DIM * 2;
  float2* tab = (float2*)w;

  k_prep<<<(PREP_E + 255) / 256, 256, 0, stream>>>(
      (const float4*)x, (const float4*)qkv_w, (const float4*)proj_w,
      (ushort4*)xb, (ushort4*)wqkvb, (ushort4*)wprojb, tab);

  k_gemm<1><<<dim3(3 * DIM / 128, MTOK / 128), 256, 0, stream>>>(
      xb, wqkvb, qkv_b, DIM, nullptr, qb, kb, vtb, tab);

  k_attn<<<512, 256, 0, stream>>>(qb, kb, vtb, aout);

  k_gemm<0><<<dim3(DIM / 128, MTOK / 128), 256, 0, stream>>>(
      aout, wprojb, proj_b, DIM, out, nullptr, nullptr, nullptr, nullptr);
}

// Round 9
// 133.699 us; speedup vs baseline: 1.3058x; 1.0109x over previous
//
#include <hip/hip_runtime.h>
#include <hip/hip_bf16.h>
#include <stdint.h>

#define DIM   1024
#define NH    16
#define HDIM  64
#define SEQ   2048
#define BATCH 2
#define BHN   32            // BATCH*NH
#define MTOK  4096          // BATCH*SEQ
#define SC2   0.18033688f   // (1/sqrt(64)) * log2(e)

using u16 = unsigned short;
using u32 = unsigned int;
typedef __attribute__((ext_vector_type(8))) short short8;   // MFMA A/B frag (8 bf16)
typedef __attribute__((ext_vector_type(4))) float f32x4;    // 16x16 MFMA C/D frag
typedef __attribute__((ext_vector_type(16))) float f32x16;  // 32x32 MFMA C/D frag

__device__ __forceinline__ u16 f2bf(float f) {
  __hip_bfloat16 h = __float2bfloat16(f);
  return *reinterpret_cast<u16*>(&h);
}
__device__ __forceinline__ u32 pk2(float lo, float hi) {
  return (u32)f2bf(lo) | ((u32)f2bf(hi) << 16);
}
// hardware packed f32->bf16 (RNE), 1 instr for 2 values
__device__ __forceinline__ u32 cvtpk(float lo, float hi) {
  u32 r;
  asm("v_cvt_pk_bf16_f32 %0, %1, %2" : "=v"(r) : "v"(lo), "v"(hi));
  return r;
}

// async global->LDS, 16B per lane. lds base must be wave-uniform; gsrc per-lane.
__device__ __forceinline__ void gload16(const void* g, void* lds) {
  __builtin_amdgcn_global_load_lds(
      (const __attribute__((address_space(1))) u32*)g,
      (__attribute__((address_space(3))) u32*)lds, 16, 0, 0);
}

// ---------------- fused prep: fp32->bf16 x3 + RoPE cos/sin table ----------------
#define PREP_A 1048576              // x: MTOK*DIM/4
#define PREP_B 1835008              // + qkv_w: 3*DIM*DIM/4
#define PREP_C 2097152              // + proj_w: DIM*DIM/4
#define PREP_E 2162688              // + tab: SEQ*32
__global__ void k_prep(const float4* __restrict__ x, const float4* __restrict__ qw,
                       const float4* __restrict__ pw, ushort4* __restrict__ xb,
                       ushort4* __restrict__ qwb, ushort4* __restrict__ pwb,
                       float2* __restrict__ tab) {
  int i = blockIdx.x * blockDim.x + threadIdx.x;
  if (i < PREP_A) {
    float4 v = x[i];
    xb[i] = make_ushort4(f2bf(v.x), f2bf(v.y), f2bf(v.z), f2bf(v.w));
  } else if (i < PREP_B) {
    int j = i - PREP_A;
    float4 v = qw[j];
    qwb[j] = make_ushort4(f2bf(v.x), f2bf(v.y), f2bf(v.z), f2bf(v.w));
  } else if (i < PREP_C) {
    int j = i - PREP_B;
    float4 v = pw[j];
    pwb[j] = make_ushort4(f2bf(v.x), f2bf(v.y), f2bf(v.z), f2bf(v.w));
  } else if (i < PREP_E) {
    int j = i - PREP_C;
    int n = j >> 5, f = j & 31;
    float inv = powf(10000.f, -(2.f * f) / 64.f);
    float s, c;
    sincosf((float)n * inv, &s, &c);
    tab[j] = make_float2(c, s);
  }
}

// ---------------- bf16 GEMM: C = A * Bt^T, 128x128 tile, BK=64 ----------------
// EPI=0: fp32 out + bias (proj). EPI=1: bias + fused RoPE + scatter to q (row-major),
// k/vt (tiled chunk-major: [bh][tile n/64][chunk][row][8elem], see k_attn).
template <int EPI>
__global__ __launch_bounds__(256, 2) void k_gemm(
    const u16* __restrict__ A, const u16* __restrict__ Bt,
    const float* __restrict__ bias, int K,
    float* __restrict__ out_f, u16* __restrict__ qb, u16* __restrict__ kb,
    u16* __restrict__ vtb, const float2* __restrict__ tab) {
  __shared__ u16 As[128 * 64];
  __shared__ u16 Bs[128 * 64];
  const int tid = threadIdx.x;
  const int wid = tid >> 6, lane = tid & 63;
  const int lq = lane & 15, g = lane >> 4;
  const int wr = wid >> 1, wc = wid & 1;
  const int brow = blockIdx.y * 128;
  const int bcol = blockIdx.x * 128;
  f32x4 acc[4][4] = {};
  const u16* Ab = A + (size_t)brow * K;
  const u16* Bb = Bt + (size_t)bcol * K;

  for (int k0 = 0; k0 < K; k0 += 64) {
#pragma unroll
    for (int t = 0; t < 4; t++) {
      int rl = wid * 32 + t * 8 + (lane >> 3);
      int cs = (lane & 7) ^ (rl & 7);
      gload16(Ab + (size_t)rl * K + k0 + cs * 8, &As[(wid * 32 + t * 8) * 64]);
      gload16(Bb + (size_t)rl * K + k0 + cs * 8, &Bs[(wid * 32 + t * 8) * 64]);
    }
    __syncthreads();
#pragma unroll
    for (int kc = 0; kc < 2; kc++) {
      short8 af[4], bfr[4];
#pragma unroll
      for (int mt = 0; mt < 4; mt++) {
        int r = wr * 64 + mt * 16 + lq;
        af[mt] = *reinterpret_cast<const short8*>(&As[r * 64 + (((kc * 4 + g) ^ (r & 7)) * 8)]);
      }
#pragma unroll
      for (int nt = 0; nt < 4; nt++) {
        int r = wc * 64 + nt * 16 + lq;
        bfr[nt] = *reinterpret_cast<const short8*>(&Bs[r * 64 + (((kc * 4 + g) ^ (r & 7)) * 8)]);
      }
#pragma unroll
      for (int mt = 0; mt < 4; mt++)
#pragma unroll
        for (int nt = 0; nt < 4; nt++)
          acc[mt][nt] = __builtin_amdgcn_mfma_f32_16x16x32_bf16(af[mt], bfr[nt], acc[mt][nt], 0, 0, 0);
    }
    __syncthreads();
  }

#pragma unroll
  for (int mt = 0; mt < 4; mt++) {
    int row0 = brow + wr * 64 + mt * 16 + g * 4;
#pragma unroll
    for (int nt = 0; nt < 4; nt++) {
      int col = bcol + wc * 64 + nt * 16 + lq;
      float bv = bias[col];
      float v[4];
#pragma unroll
      for (int r = 0; r < 4; r++) v[r] = acc[mt][nt][r] + bv;
      if (EPI == 0) {
#pragma unroll
        for (int r = 0; r < 4; r++) out_f[(size_t)(row0 + r) * DIM + col] = v[r];
      } else {
        int which = col >> 10, hd = col & 1023, hdh = hd >> 6, d = hd & 63;
        int bb = row0 >> 11, n0 = row0 & 2047;
        int bh = bb * NH + hdh;
        if (which == 2) {
          // V^T tiled: [bh][n/64][kvchunk=(n&63)/8][row=d][n&7]; 4 consecutive n -> 8B store
          uint2 pv = make_uint2(pk2(v[0], v[1]), pk2(v[2], v[3]));
          size_t idx = ((((size_t)bh * 32 + (n0 >> 6)) * 8 + ((n0 >> 3) & 7)) * 64 + d) * 8 + (n0 & 7);
          *reinterpret_cast<uint2*>(&vtb[idx]) = pv;
        } else {
#pragma unroll
          for (int r = 0; r < 4; r++) {
            int n = n0 + r;
            // fused RoPE: partner value (col^1) lives in adjacent lane
            float p = __shfl_xor(v[r], 1);
            float2 cs = tab[n * 32 + (d >> 1)];
            float vv = (d & 1) ? fmaf(p, cs.y, v[r] * cs.x)   // o' = e*s + o*c
                               : fmaf(-p, cs.y, v[r] * cs.x); // e' = e*c - o*s
            u16 xo = f2bf(vv);
            if (which == 0) {
              qb[((size_t)bh * SEQ + n) * HDIM + d] = xo;     // row-major
            } else {
              // K tiled: [bh][n/64][dchunk=d/8][row=n&63][d&7]
              size_t idx = ((((size_t)bh * 32 + (n >> 6)) * 8 + (d >> 3)) * 64 + (n & 63)) * 8 + (d & 7);
              kb[idx] = xo;
            }
          }
        }
      }
    }
  }
}

// ---------------- flash attention: R8 pipeline + chunk-major conflict-free LDS ----------------
// grid 512 (XCD-swizzled: 4 heads/XCD), 256 thr = 4 waves x 32 q-rows; shared 64-kv
// stream in 3 rotating LDS buffers. ONE barrier per tile, counted vmcnt(4).
// K/V global pre-tiled chunk-major: tile = 8 chunk-blocks x [row 0..63][16B].
// LDS = identical layout -> stage is 1KB contiguous gload per chunk-block and every
// frag read is lane->consecutive-16B: zero bank conflicts, zero swizzle math.
// S^T = K*Q^T (32x32x16), per-lane online softmax, cvt_pk+permlane32_swap pack,
// O^T = V^T*P^T. Defer-max rescale.
__global__ __launch_bounds__(256, 2) void k_attn(
    const u16* __restrict__ qg, const u16* __restrict__ kg,
    const u16* __restrict__ vg, u16* __restrict__ aout) {
  __shared__ __align__(16) char smem[49152];   // 3 buf x [K 8KB | V 8KB]
  const int tid = threadIdx.x;
  const int wid = tid >> 6, lane = tid & 63;
  const int l31 = lane & 31, h = lane >> 5;

  // XCD-aware decode: bid&7 = XCD; 4 consecutive heads per XCD (2MB KV / XCD-L2)
  const int bid = blockIdx.x;
  const int xcd = bid & 7, slot = bid >> 3;      // slot 0..63
  const int bh = xcd * 4 + (slot >> 4);
  const int qt = slot & 15;
  const int b = bh >> 4, hh = bh & 15;
  const int q0 = qt * 128 + wid * 32;            // this wave's 32 q-rows

  const u16* kbase = kg + (size_t)bh * SEQ * HDIM;   // 32 tiles x 4096 u16
  const u16* vbase = vg + (size_t)bh * SEQ * HDIM;

  // Q B-frags: chunk c -> d = c*16 + h*8 + j
  const u16* qrow = qg + ((size_t)bh * SEQ + q0 + l31) * HDIM;
  short8 qf[4];
#pragma unroll
  for (int c = 0; c < 4; c++)
    qf[c] = *reinterpret_cast<const short8*>(qrow + c * 16 + h * 8);

  // chunk-major frag offsets: chunk block (2c+h), row l31 (+512B for rows 32..63)
  int koff[4];
#pragma unroll
  for (int c = 0; c < 4; c++)
    koff[c] = (2 * c + h) * 1024 + l31 * 16;

  f32x16 oA = {}, oB = {};
  float m = -INFINITY, lsum = 0.f;

  // stage one 64-kv tile: wave stages K chunk-blocks {wid, wid+4} and V ditto.
  // Each gload = 1KB contiguous global -> 1KB contiguous LDS (lane -> row).
  auto stage = [&](int buf, int tidx) {
    char* kd = smem + buf * 16384;
    const u16* kt = kbase + (size_t)tidx * 4096 + lane * 8;
    const u16* vt = vbase + (size_t)tidx * 4096 + lane * 8;
#pragma unroll
    for (int i = 0; i < 2; i++) {
      int g = wid + i * 4;
      gload16(kt + g * 512, kd + g * 1024);
      gload16(vt + g * 512, kd + 8192 + g * 1024);
    }
  };

  stage(0, 0);
  stage(1, 1);

  const int NT = SEQ / 64;
  int cur = 0, nxt = 2;                          // buf index of tile t, and of tile t+2
  for (int t = 0; t < NT; ++t) {
    if (t < NT - 1) asm volatile("s_waitcnt vmcnt(4)" ::: "memory");
    else            asm volatile("s_waitcnt vmcnt(0)" ::: "memory");
    __builtin_amdgcn_s_barrier();                // tile t ready for everyone

    const char* kbp = smem + cur * 16384;
    const char* vbp = kbp + 8192;

    // S^T = K * Q^T : s0 = kv 0..31 of tile, s1 = kv 32..63; lane col q = l31
    f32x16 s0 = {}, s1 = {};
    __builtin_amdgcn_s_setprio(1);
#pragma unroll
    for (int c = 0; c < 4; c++) {
      short8 k0 = *reinterpret_cast<const short8*>(kbp + koff[c]);
      short8 k1 = *reinterpret_cast<const short8*>(kbp + koff[c] + 512);
      s0 = __builtin_amdgcn_mfma_f32_32x32x16_bf16(k0, qf[c], s0, 0, 0, 0);
      s1 = __builtin_amdgcn_mfma_f32_32x32x16_bf16(k1, qf[c], s1, 0, 0, 0);
    }
    __builtin_amdgcn_s_setprio(0);

    // V A-frags issued early: LDS latency hides under softmax VALU
    short8 vf0[4], vf1[4];
#pragma unroll
    for (int c = 0; c < 4; c++) {
      vf0[c] = *reinterpret_cast<const short8*>(vbp + koff[c]);
      vf1[c] = *reinterpret_cast<const short8*>(vbp + koff[c] + 512);
    }

    // prefetch tile t+2 into the buffer consumed at iter t-1 (safe: barrier t
    // ordered everyone's t-1 reads before this write)
    if (t + 2 < NT) stage(nxt, t + 2);

    // online softmax; lane owns q = l31 (paired across lane^32)
    float tm[8];
#pragma unroll
    for (int r = 0; r < 8; r++)
      tm[r] = fmaxf(fmaxf(s0[r], s1[r]), fmaxf(s0[r + 8], s1[r + 8]));
    float ta = fmaxf(fmaxf(tm[0], tm[1]), tm[2]);
    float tb = fmaxf(fmaxf(tm[3], tm[4]), tm[5]);
    float tc = fmaxf(tm[6], tm[7]);
    float tmax = fmaxf(fmaxf(ta, tb), tc);
    tmax = fmaxf(tmax, __shfl_xor(tmax, 32));

    float alpha = 1.f;
    if (__any(tmax - m > 61.0f)) {     // defer-max: p bounded by 2^11
      float mnew = fmaxf(m, tmax);
      alpha = exp2f((m - mnew) * SC2);
      m = mnew;
#pragma unroll
      for (int r = 0; r < 16; r++) { oA[r] *= alpha; oB[r] *= alpha; }
    }
    const float nms = -m * SC2;
#pragma unroll
    for (int r = 0; r < 16; r++) s0[r] = exp2f(fmaf(s0[r], SC2, nms));
#pragma unroll
    for (int r = 0; r < 16; r++) s1[r] = exp2f(fmaf(s1[r], SC2, nms));
    float pa = 0.f, pb = 0.f, pc = 0.f, pd = 0.f;
#pragma unroll
    for (int r = 0; r < 4; r++) {
      pa += s0[r] + s0[r + 4];
      pb += s0[r + 8] + s0[r + 12];
      pc += s1[r] + s1[r + 4];
      pd += s1[r + 8] + s1[r + 12];
    }
    float psum = (pa + pb) + (pc + pd);
    psum += __shfl_xor(psum, 32);
    lsum = lsum * alpha + psum;

    // pack P to bf16 B-frags: 4 cvt_pk + 2 permlane32_swap per chunk (T12)
    short8 pf[4];
    {
      union { u32 u[4]; short8 v; } pp;
      u32 a0, a1, b0, b1;
      a0 = cvtpk(s0[0], s0[1]);  a1 = cvtpk(s0[2], s0[3]);
      b0 = cvtpk(s0[4], s0[5]);  b1 = cvtpk(s0[6], s0[7]);
      { auto r0 = __builtin_amdgcn_permlane32_swap(a0, b0, false, false);
        auto r1 = __builtin_amdgcn_permlane32_swap(a1, b1, false, false);
        pp.u[0] = r0[0]; pp.u[1] = r1[0]; pp.u[2] = r0[1]; pp.u[3] = r1[1]; pf[0] = pp.v; }
      a0 = cvtpk(s0[8], s0[9]);   a1 = cvtpk(s0[10], s0[11]);
      b0 = cvtpk(s0[12], s0[13]); b1 = cvtpk(s0[14], s0[15]);
      { auto r0 = __builtin_amdgcn_permlane32_swap(a0, b0, false, false);
        auto r1 = __builtin_amdgcn_permlane32_swap(a1, b1, false, false);
        pp.u[0] = r0[0]; pp.u[1] = r1[0]; pp.u[2] = r0[1]; pp.u[3] = r1[1]; pf[1] = pp.v; }
      a0 = cvtpk(s1[0], s1[1]);  a1 = cvtpk(s1[2], s1[3]);
      b0 = cvtpk(s1[4], s1[5]);  b1 = cvtpk(s1[6], s1[7]);
      { auto r0 = __builtin_amdgcn_permlane32_swap(a0, b0, false, false);
        auto r1 = __builtin_amdgcn_permlane32_swap(a1, b1, false, false);
        pp.u[0] = r0[0]; pp.u[1] = r1[0]; pp.u[2] = r0[1]; pp.u[3] = r1[1]; pf[2] = pp.v; }
      a0 = cvtpk(s1[8], s1[9]);   a1 = cvtpk(s1[10], s1[11]);
      b0 = cvtpk(s1[12], s1[13]); b1 = cvtpk(s1[14], s1[15]);
      { auto r0 = __builtin_amdgcn_permlane32_swap(a0, b0, false, false);
        auto r1 = __builtin_amdgcn_permlane32_swap(a1, b1, false, false);
        pp.u[0] = r0[0]; pp.u[1] = r1[0]; pp.u[2] = r0[1]; pp.u[3] = r1[1]; pf[3] = pp.v; }
    }

    // O^T += V^T * P^T : oA = d 0..31, oB = d 32..63; lane col q = l31
    __builtin_amdgcn_s_setprio(1);
#pragma unroll
    for (int c = 0; c < 4; c++) {
      oA = __builtin_amdgcn_mfma_f32_32x32x16_bf16(vf0[c], pf[c], oA, 0, 0, 0);
      oB = __builtin_amdgcn_mfma_f32_32x32x16_bf16(vf1[c], pf[c], oB, 0, 0, 0);
    }
    __builtin_amdgcn_s_setprio(0);

    cur = cur == 2 ? 0 : cur + 1;
    nxt = nxt == 2 ? 0 : nxt + 1;
  }

  // epilogue: d = {0,32} + 8g + 4h + i ; n = q0 + l31
  float invl = 1.0f / lsum;
  int n = q0 + l31;
  u16* op = aout + ((size_t)(b * SEQ + n)) * DIM + hh * HDIM;
#pragma unroll
  for (int g = 0; g < 4; g++) {
    u32 w0 = pk2(oA[4 * g] * invl, oA[4 * g + 1] * invl);
    u32 w1 = pk2(oA[4 * g + 2] * invl, oA[4 * g + 3] * invl);
    *reinterpret_cast<uint2*>(op + 8 * g + 4 * h) = make_uint2(w0, w1);
    u32 x0 = pk2(oB[4 * g] * invl, oB[4 * g + 1] * invl);
    u32 x1 = pk2(oB[4 * g + 2] * invl, oB[4 * g + 3] * invl);
    *reinterpret_cast<uint2*>(op + 32 + 8 * g + 4 * h) = make_uint2(x0, x1);
  }
}

// ---------------- launch ----------------
extern "C" void kernel_launch(void* const* d_in, const int* in_sizes, int n_in,
                              void* d_out, int out_size, void* d_ws, size_t ws_size,
                              hipStream_t stream) {
  (void)in_sizes; (void)n_in; (void)out_size; (void)ws_size;
  const float* x      = (const float*)d_in[0];
  const float* qkv_w  = (const float*)d_in[1];
  const float* qkv_b  = (const float*)d_in[2];
  const float* proj_w = (const float*)d_in[3];
  const float* proj_b = (const float*)d_in[4];
  float* out = (float*)d_out;

  char* w = (char*)d_ws;
  u16* xb     = (u16*)w;  w += (size_t)MTOK * DIM * 2;
  u16* wqkvb  = (u16*)w;  w += (size_t)3 * DIM * DIM * 2;
  u16* wprojb = (u16*)w;  w += (size_t)DIM * DIM * 2;
  u16* qb     = (u16*)w;  w += (size_t)BHN * SEQ * HDIM * 2;
  u16* kb     = (u16*)w;  w += (size_t)BHN * SEQ * HDIM * 2;
  u16* vtb    = (u16*)w;  w += (size_t)BHN * SEQ * HDIM * 2;
  u16* aout   = (u16*)w;  w += (size_t)MTOK * DIM * 2;
  float2* tab = (float2*)w;

  k_prep<<<(PREP_E + 255) / 256, 256, 0, stream>>>(
      (const float4*)x, (const float4*)qkv_w, (const float4*)proj_w,
      (ushort4*)xb, (ushort4*)wqkvb, (ushort4*)wprojb, tab);

  k_gemm<1><<<dim3(3 * DIM / 128, MTOK / 128), 256, 0, stream>>>(
      xb, wqkvb, qkv_b, DIM, nullptr, qb, kb, vtb, tab);

  k_attn<<<512, 256, 0, stream>>>(qb, kb, vtb, aout);

  k_gemm<0><<<dim3(DIM / 128, MTOK / 128), 256, 0, stream>>>(
      aout, wprojb, proj_b, DIM, out, nullptr, nullptr, nullptr, nullptr);
}